// Round 13
// baseline (1499.647 us; speedup 1.0000x reference)
//
#include <hip/hip_runtime.h>
#include <hip/hip_bf16.h>
#include <hip/hip_fp16.h>

typedef _Float16 f16;
typedef _Float16 f16x8 __attribute__((ext_vector_type(8)));
typedef float f32x4 __attribute__((ext_vector_type(4)));

constexpr int EE     = 512;
constexpr int NMEM   = 50000;
constexpr int BQ     = 8192;
constexpr int NSEG   = 16;
constexpr int SEGLEN = NMEM / NSEG;              // 3125 (exact)
constexpr int KVT    = 32;                       // keys per tile
constexpr int NT32   = (SEGLEN + KVT - 1) / KVT; // 98
constexpr int TILE_E = KVT * EE;                 // 16384 f16 elements per frag-tile
constexpr int NC     = 5;                        // candidates kept per segment
constexpr int NCAND  = NSEG * NC;                // 80
constexpr int NRES   = 10;                       // exact-rescored candidates

// pack 12-bit local index into low mantissa bits of score (compare-as-float safe:
// perturbation <= 0.125 at |score|~500, far below rank-5..10 gaps; rescore is exact)
__device__ static inline float pack_si(float s, int li) {
  return __uint_as_float((__float_as_uint(s) & 0xFFFFF000u) | (unsigned)li);
}

// ---------------- prep: row norms (+ optional f16 row-major copy for big tier) ----------------
__global__ __launch_bounds__(256) void k_prep_keys(const float* __restrict__ mk,
                                                   f16* __restrict__ kh,      // nullable
                                                   float* __restrict__ sq32,
                                                   double* __restrict__ sq64) {
  int row  = blockIdx.x * 4 + (threadIdx.x >> 6);
  int lane = threadIdx.x & 63;
  const float4* src = (const float4*)(mk + (size_t)row * EE) + lane * 2;
  float4 a = src[0], b = src[1];
  double s = (double)a.x*a.x + (double)a.y*a.y + (double)a.z*a.z + (double)a.w*a.w
           + (double)b.x*b.x + (double)b.y*b.y + (double)b.z*b.z + (double)b.w*b.w;
  if (kh) {
    f16x8 h;
    h[0]=(f16)a.x; h[1]=(f16)a.y; h[2]=(f16)a.z; h[3]=(f16)a.w;
    h[4]=(f16)b.x; h[5]=(f16)b.y; h[6]=(f16)b.z; h[7]=(f16)b.w;
    *((f16x8*)(kh + (size_t)row * EE) + lane) = h;
  }
  #pragma unroll
  for (int o = 32; o > 0; o >>= 1) s += __shfl_down(s, o);
  if (lane == 0) { sq64[row] = s; sq32[row] = (float)s; }
}

// fragment-major K layout: tile (s,t) -> 32 contiguous 1KB MFMA A-fragments.
// frag f = ks*2+half holds keys [t*32 + half*16 .. +16) at depth cols [ks*32 .. +32).
// lane l element: Khf[(s*98+t)*16384 + f*512 + l*8] = mk[s*3125 + t*32 + half*16 + (l&15)][ks*32 + (l>>4)*8]
__global__ __launch_bounds__(256) void k_prep_kf(const float* __restrict__ mk,
                                                 const float* __restrict__ sq32,
                                                 f16* __restrict__ Khf,
                                                 float* __restrict__ sqsP) {
  const int t = blockIdx.x, s = blockIdx.y;
  const int tid = threadIdx.x;
  const int fg = tid >> 6, l6 = tid & 63, lc = l6 & 15, lp = l6 >> 4;
  const size_t tb = (size_t)(s * NT32 + t) * TILE_E;
  const int kk = t * KVT;
  #pragma unroll
  for (int j = 0; j < 8; ++j) {
    int f = fg + j * 4;
    int ks = f >> 1, half = f & 1;
    int keyl = kk + half * 16 + lc;
    f16x8 h;
    #pragma unroll
    for (int i = 0; i < 8; ++i) h[i] = (f16)0.f;
    if (keyl < SEGLEN) {
      const float* src = mk + (size_t)(s * SEGLEN + keyl) * EE + ks * 32 + lp * 8;
      float4 x0 = *(const float4*)(src);
      float4 x1 = *(const float4*)(src + 4);
      h[0]=(f16)x0.x; h[1]=(f16)x0.y; h[2]=(f16)x0.z; h[3]=(f16)x0.w;
      h[4]=(f16)x1.x; h[5]=(f16)x1.y; h[6]=(f16)x1.z; h[7]=(f16)x1.w;
    }
    *(f16x8*)(Khf + tb + (size_t)f * 512 + (size_t)l6 * 8) = h;
  }
  if (tid < KVT) {
    int keyl = kk + tid;
    sqsP[(size_t)(s * NT32 + t) * KVT + tid] =
        (keyl < SEGLEN) ? sq32[s * SEGLEN + keyl] : 6.0e38f;  // +inf poison -> score -inf
  }
}

// generic f32 -> f16 row copy (rows of EE)
__global__ __launch_bounds__(256) void k_prep_f16(const float* __restrict__ src,
                                                  f16* __restrict__ dst) {
  int row  = blockIdx.x * 4 + (threadIdx.x >> 6);
  int lane = threadIdx.x & 63;
  const float4* s = (const float4*)(src + (size_t)row * EE) + lane * 2;
  float4 a = s[0], b = s[1];
  f16x8 h;
  h[0]=(f16)a.x; h[1]=(f16)a.y; h[2]=(f16)a.z; h[3]=(f16)a.w;
  h[4]=(f16)b.x; h[5]=(f16)b.y; h[6]=(f16)b.z; h[7]=(f16)b.w;
  *((f16x8*)(dst + (size_t)row * EE) + lane) = h;
}

// ---------------- compose weights: Wc_m = Win_m @ W_m (f32 acc -> fp16 out) ----------------
__global__ __launch_bounds__(256) void k_compose(const float* __restrict__ Wq, const float* __restrict__ Wk,
                                                 const float* __restrict__ Wv, const float* __restrict__ Wiq,
                                                 const float* __restrict__ Wik, const float* __restrict__ Wiv,
                                                 f16* __restrict__ Wc) {
  int m = blockIdx.z;
  const float* A = (m == 0) ? Wiq : ((m == 1) ? Wik : Wiv);
  const float* B = (m == 0) ? Wq  : ((m == 1) ? Wk  : Wv);
  f16* C = Wc + (size_t)m * EE * EE;
  __shared__ float As[64][33];
  __shared__ float Bs[32][65];
  int i0 = blockIdx.x * 64, j0 = blockIdx.y * 64;
  int tx = threadIdx.x & 15, ty = threadIdx.x >> 4;
  float acc[4][4] = {};
  for (int kb = 0; kb < EE; kb += 32) {
    __syncthreads();
    #pragma unroll
    for (int v = 0; v < 8; ++v) {
      int idx = threadIdx.x + v * 256;
      As[idx >> 5][idx & 31] = A[(size_t)(i0 + (idx >> 5)) * EE + kb + (idx & 31)];
    }
    #pragma unroll
    for (int v = 0; v < 8; ++v) {
      int idx = threadIdx.x + v * 256;
      Bs[idx >> 6][idx & 63] = B[(size_t)(kb + (idx >> 6)) * EE + j0 + (idx & 63)];
    }
    __syncthreads();
    for (int t = 0; t < 32; ++t) {
      float av[4], bv[4];
      #pragma unroll
      for (int u = 0; u < 4; ++u) av[u] = As[ty*4+u][t];
      #pragma unroll
      for (int u = 0; u < 4; ++u) bv[u] = Bs[t][tx*4+u];
      #pragma unroll
      for (int a = 0; a < 4; ++a)
        #pragma unroll
        for (int b = 0; b < 4; ++b) acc[a][b] = fmaf(av[a], bv[b], acc[a][b]);
    }
  }
  #pragma unroll
  for (int a = 0; a < 4; ++a)
    #pragma unroll
    for (int b = 0; b < 4; ++b)
      C[(size_t)(i0 + ty*4 + a) * EE + j0 + tx*4 + b] = (f16)acc[a][b];
}

__global__ void k_bias(const float* __restrict__ Wiq, const float* __restrict__ Wik,
                       const float* __restrict__ Wiv, const float* __restrict__ bqv,
                       const float* __restrict__ bkv, const float* __restrict__ bvv,
                       const float* __restrict__ b_in, float* __restrict__ bc) {
  int m = blockIdx.x;
  const float* Wi = (m == 0) ? Wiq : ((m == 1) ? Wik : Wiv);
  const float* bb = (m == 0) ? bqv : ((m == 1) ? bkv : bvv);
  for (int i = threadIdx.x; i < EE; i += blockDim.x) {
    float s = 0.f;
    for (int t = 0; t < EE; ++t) s = fmaf(Wi[(size_t)i * EE + t], bb[t], s);
    bc[m * EE + i] = s + b_in[m * EE + i];
  }
}

__global__ void k_cvtw(const float* __restrict__ W, f16* __restrict__ Wo) {
  int i = blockIdx.x * 256 + threadIdx.x;
  Wo[i] = (f16)W[i];
}

// ---------------- stage 1: LDS-free swapped-operand fp16 MFMA scores ----------------
// K fragments read directly global->register from the fragment-major Khf (L1/L2-served,
// XCD-swizzled so one segment's 64 blocks share one XCD L2). No barriers in the loop.
__global__ __launch_bounds__(256, 2) void k_stage1(const f16* __restrict__ Qh,
                                                   const f16* __restrict__ Khf,
                                                   const float* __restrict__ sqsP,
                                                   int* __restrict__ part_i,
                                                   float* __restrict__ part_s) {
  // dispatch-aware swizzle: HW id h -> XCD h%8 (observed round-robin); give XCD x
  // segment x (pass 1) / 8+x (pass 2) so a segment's stream stays in one L2.
  const int h   = blockIdx.x;               // 0..1023
  const int seg = (h & 7) + 8 * (h >> 9);
  const int rb  = (h >> 3) & 63;
  const int tid = threadIdx.x;
  const int w   = tid >> 6;                 // wave 0..3
  const int l   = tid & 63;
  const int lc  = l & 15, lp = l >> 4;

  const int rowbase = rb * 128 + w * 32;
  f16x8 a0[16], a1[16];
  {
    const f16* base0 = Qh + (size_t)(rowbase + lc) * EE + lp * 8;
    const f16* base1 = base0 + (size_t)16 * EE;
    #pragma unroll
    for (int ks = 0; ks < 16; ++ks) {
      asm volatile("global_load_dwordx4 %0, %1, off"
                   : "=v"(a0[ks]) : "v"(base0 + ks * 32) : "memory");
      asm volatile("global_load_dwordx4 %0, %1, off"
                   : "=v"(a1[ks]) : "v"(base1 + ks * 32) : "memory");
    }
    asm volatile("s_waitcnt vmcnt(0)" ::: "memory");
    __builtin_amdgcn_sched_barrier(0);
  }

  float ts0[NC], ts1[NC];
  #pragma unroll
  for (int i = 0; i < NC; ++i) { ts0[i] = -3.0e38f; ts1[i] = -3.0e38f; }

#define INS1(TS, PV) do { \
    if (__ballot((PV) > TS[NC-1])) { \
      float _nv = ((PV) > TS[NC-1]) ? (PV) : TS[NC-1]; \
      TS[NC-1] = _nv; \
      _Pragma("unroll") \
      for (int _i = NC - 1; _i > 0; --_i) { \
        float _mx = fmaxf(TS[_i], TS[_i-1]); \
        float _mn = fminf(TS[_i], TS[_i-1]); \
        TS[_i-1] = _mx; TS[_i] = _mn; \
      } \
    } \
  } while (0)

  const f16*   kf_base = Khf  + (size_t)seg * NT32 * TILE_E + (size_t)l * 8;
  const float* sq_base = sqsP + (size_t)seg * NT32 * KVT;

  for (int t = 0; t < NT32; ++t) {
    const f16*   kfb = kf_base + (size_t)t * TILE_E;
    const float* sqb = sq_base + t * KVT;
    f32x4 q0 = *(const f32x4*)(sqb + lp * 4);
    f32x4 q1 = *(const f32x4*)(sqb + 16 + lp * 4);

    f32x4 A00 = {0,0,0,0}, A01 = {0,0,0,0}, A10 = {0,0,0,0}, A11 = {0,0,0,0};
    #pragma unroll
    for (int ks = 0; ks < 16; ++ks) {
      f16x8 kf0 = *(const f16x8*)(kfb + (2 * ks + 0) * 512);
      f16x8 kf1 = *(const f16x8*)(kfb + (2 * ks + 1) * 512);
      A00 = __builtin_amdgcn_mfma_f32_16x16x32_f16(kf0, a0[ks], A00, 0, 0, 0);
      A01 = __builtin_amdgcn_mfma_f32_16x16x32_f16(kf0, a1[ks], A01, 0, 0, 0);
      A10 = __builtin_amdgcn_mfma_f32_16x16x32_f16(kf1, a0[ks], A10, 0, 0, 0);
      A11 = __builtin_amdgcn_mfma_f32_16x16x32_f16(kf1, a1[ks], A11, 0, 0, 0);
    }
    f32x4 s00 = 2.0f * A00 - q0;
    f32x4 s01 = 2.0f * A01 - q0;
    f32x4 s10 = 2.0f * A10 - q1;
    f32x4 s11 = 2.0f * A11 - q1;
    const int li0 = t * KVT + lp * 4;   // 12-bit local key index (<= 3135)
    const int li1 = li0 + 16;
    #pragma unroll
    for (int r = 0; r < 4; ++r) {
      INS1(ts0, pack_si(s00[r], li0 + r));
      INS1(ts0, pack_si(s10[r], li1 + r));
      INS1(ts1, pack_si(s01[r], li0 + r));
      INS1(ts1, pack_si(s11[r], li1 + r));
    }
  }

  // merge key-stripes: lanes {lc, lc+16, lc+32, lc+48} hold disjoint stripes of same q-rows
  #pragma unroll
  for (int d = 16; d <= 32; d <<= 1) {
    float os[NC];
    #pragma unroll
    for (int i = 0; i < NC; ++i) os[i] = __shfl_xor(ts0[i], d);
    #pragma unroll
    for (int j = 0; j < NC; ++j) INS1(ts0, os[j]);
    #pragma unroll
    for (int i = 0; i < NC; ++i) os[i] = __shfl_xor(ts1[i], d);
    #pragma unroll
    for (int j = 0; j < NC; ++j) INS1(ts1, os[j]);
  }
#undef INS1
  const int seg_start = seg * SEGLEN;
  if (l < 16) {
    int row = rowbase + lc;
    #pragma unroll
    for (int i = 0; i < NC; ++i) {
      unsigned u = __float_as_uint(ts0[i]);
      part_i[(size_t)row * NCAND + seg * NC + i] = seg_start + (int)(u & 0xFFFu);
      part_s[(size_t)row * NCAND + seg * NC + i] = ts0[i];
    }
  } else if (l < 32) {
    int row = rowbase + 16 + lc;
    #pragma unroll
    for (int i = 0; i < NC; ++i) {
      unsigned u = __float_as_uint(ts1[i]);
      part_i[(size_t)row * NCAND + seg * NC + i] = seg_start + (int)(u & 0xFFFu);
      part_s[(size_t)row * NCAND + seg * NC + i] = ts1[i];
    }
  }
}

// ---------------- stage 2: noisy top-10 of 80, exact f64 rescore -> top-5 ----------------
__global__ __launch_bounds__(64) void k_rescore(const float* __restrict__ Q,
                                                const float* __restrict__ mk,
                                                const double* __restrict__ sq64,
                                                const int* __restrict__ part_i,
                                                const float* __restrict__ part_s,
                                                int* __restrict__ idx5) {
  const int row = blockIdx.x;
  const int l = threadIdx.x;
  const float* Qr = Q + (size_t)row * EE;
  float q[8];
  #pragma unroll
  for (int i = 0; i < 8; ++i) q[i] = Qr[l + 64*i];
  float s0 = part_s[(size_t)row * NCAND + l];
  int   i0 = part_i[(size_t)row * NCAND + l];
  float s1 = (l < NCAND - 64) ? part_s[(size_t)row * NCAND + 64 + l] : -3.0e38f;
  int   i1 = (l < NCAND - 64) ? part_i[(size_t)row * NCAND + 64 + l] : 0;

  double bs[5] = {-1e300, -1e300, -1e300, -1e300, -1e300};
  int    bi[5] = {0, 0, 0, 0, 0};
  #pragma unroll
  for (int p = 0; p < NRES; ++p) {
    bool pick0 = (s0 >= s1);
    float m  = pick0 ? s0 : s1;
    int   mi = pick0 ? i0 : i1;
    int   code = (l << 1) | (pick0 ? 0 : 1);
    #pragma unroll
    for (int o = 32; o > 0; o >>= 1) {
      float mo = __shfl_xor(m, o);
      int   io = __shfl_xor(mi, o);
      int   co = __shfl_xor(code, o);
      if (mo > m || (mo == m && co < code)) { m = mo; mi = io; code = co; }
    }
    if ((code >> 1) == l) { if (code & 1) s1 = -3.0e38f; else s0 = -3.0e38f; }
    const float* kr = mk + (size_t)mi * EE;
    double pd = 0.0;
    #pragma unroll
    for (int i = 0; i < 8; ++i) pd += (double)q[i] * (double)kr[l + 64*i];
    #pragma unroll
    for (int o = 32; o > 0; o >>= 1) pd += __shfl_down(pd, o);
    if (l == 0) {
      double s = 2.0 * pd - sq64[mi];
      if (s > bs[4]) {
        bs[4] = s; bi[4] = mi;
        #pragma unroll
        for (int i = 4; i > 0; --i) {
          if (bs[i] > bs[i-1]) {
            double tf = bs[i]; bs[i] = bs[i-1]; bs[i-1] = tf;
            int    tx = bi[i]; bi[i] = bi[i-1]; bi[i-1] = tx;
          }
        }
      }
    }
  }
  if (l == 0) {
    #pragma unroll
    for (int i = 0; i < 5; ++i) idx5[(size_t)row*5 + i] = bi[i];
  }
}

// ---------------- unified 128x64-tile fp16 MFMA GEMM: C = A(rows) @ B^T + bias ----------------
template <int GATHER, int AF16, int OUTF32>
__global__ __launch_bounds__(256) void k_pgemm128(const int* __restrict__ gidx, const void* __restrict__ Asrc,
                                                  const f16* __restrict__ B, const float* __restrict__ bias,
                                                  void* __restrict__ outp) {
  __shared__ f16 As[128][72];
  __shared__ f16 Bs[64][72];
  const int tid = threadIdx.x;
  const int wv = tid >> 6, l = tid & 63, lc = l & 15, lp = l >> 4;
  const int m0 = blockIdx.x * 128, n0 = blockIdx.y * 64;
  const int r0 = tid >> 3;
  const int cb = (tid & 7) * 8;
  const f16*   arf[4];
  const float* ar32[4];
  #pragma unroll
  for (int v = 0; v < 4; ++v) {
    int row = m0 + r0 + v * 32;
    int gi = GATHER ? gidx[row] : row;
    if (AF16) arf[v]  = (const f16*)Asrc + (size_t)gi * EE;
    else      ar32[v] = (const float*)Asrc + (size_t)gi * EE;
  }
  const f16* br0 = B + (size_t)(n0 + r0) * EE;
  const f16* br1 = B + (size_t)(n0 + r0 + 32) * EE;
  f32x4 acc[2][4] = {{{0,0,0,0},{0,0,0,0},{0,0,0,0},{0,0,0,0}},
                     {{0,0,0,0},{0,0,0,0},{0,0,0,0},{0,0,0,0}}};
  for (int kb = 0; kb < EE; kb += 64) {
    __syncthreads();
    #pragma unroll
    for (int v = 0; v < 4; ++v) {
      if (AF16) {
        *(f16x8*)&As[r0 + v*32][cb] = *(const f16x8*)(arf[v] + kb + cb);
      } else {
        float4 x0 = *(const float4*)(ar32[v] + kb + cb);
        float4 x1 = *(const float4*)(ar32[v] + kb + cb + 4);
        f16x8 h;
        h[0]=(f16)x0.x; h[1]=(f16)x0.y; h[2]=(f16)x0.z; h[3]=(f16)x0.w;
        h[4]=(f16)x1.x; h[5]=(f16)x1.y; h[6]=(f16)x1.z; h[7]=(f16)x1.w;
        *(f16x8*)&As[r0 + v*32][cb] = h;
      }
    }
    *(f16x8*)&Bs[r0][cb]      = *(const f16x8*)(br0 + kb + cb);
    *(f16x8*)&Bs[r0 + 32][cb] = *(const f16x8*)(br1 + kb + cb);
    __syncthreads();
    #pragma unroll
    for (int ks = 0; ks < 2; ++ks) {
      f16x8 a0 = *(const f16x8*)&As[wv*32 + lc][ks*32 + lp*8];
      f16x8 a1 = *(const f16x8*)&As[wv*32 + 16 + lc][ks*32 + lp*8];
      #pragma unroll
      for (int f = 0; f < 4; ++f) {
        f16x8 b = *(const f16x8*)&Bs[f*16 + lc][ks*32 + lp*8];
        acc[0][f] = __builtin_amdgcn_mfma_f32_16x16x32_f16(a0, b, acc[0][f], 0, 0, 0);
        acc[1][f] = __builtin_amdgcn_mfma_f32_16x16x32_f16(a1, b, acc[1][f], 0, 0, 0);
      }
    }
  }
  #pragma unroll
  for (int g = 0; g < 2; ++g) {
    #pragma unroll
    for (int f = 0; f < 4; ++f) {
      int col = n0 + f*16 + lc;
      float bsv = bias[col];
      #pragma unroll
      for (int rr = 0; rr < 4; ++rr) {
        int row = m0 + wv*32 + g*16 + lp*4 + rr;
        float v = acc[g][f][rr] + bsv;
        if (OUTF32) ((float*)outp)[(size_t)row * EE + col] = v;
        else        ((f16*)outp)[(size_t)row * EE + col] = (f16)v;
      }
    }
  }
}

// ---------------- 5-key MHA (H=8, d=64), f32 compute ----------------
__global__ __launch_bounds__(256) void k_attn(const f16* __restrict__ qp, const f16* __restrict__ kp,
                                              const f16* __restrict__ vp, f16* __restrict__ ao) {
  int row = blockIdx.x * 4 + (threadIdx.x >> 6);
  int l = threadIdx.x & 63;
  int h = l >> 3, sl = l & 7;
  const f16* q = qp + (size_t)row * EE + h * 64 + sl * 8;
  float qv[8];
  #pragma unroll
  for (int i = 0; i < 8; ++i) qv[i] = (float)q[i];
  float sc[5];
  #pragma unroll
  for (int j = 0; j < 5; ++j) {
    const f16* kr = kp + ((size_t)row * 5 + j) * EE + h * 64 + sl * 8;
    float p = 0.f;
    #pragma unroll
    for (int i = 0; i < 8; ++i) p = fmaf(qv[i], (float)kr[i], p);
    p += __shfl_xor(p, 1); p += __shfl_xor(p, 2); p += __shfl_xor(p, 4);
    sc[j] = p * 0.125f;
  }
  float mx = fmaxf(fmaxf(fmaxf(sc[0], sc[1]), fmaxf(sc[2], sc[3])), sc[4]);
  float sum = 0.f;
  #pragma unroll
  for (int j = 0; j < 5; ++j) { sc[j] = __expf(sc[j] - mx); sum += sc[j]; }
  float inv = 1.0f / sum;
  float o[8] = {};
  #pragma unroll
  for (int j = 0; j < 5; ++j) {
    const f16* vr = vp + ((size_t)row * 5 + j) * EE + h * 64 + sl * 8;
    float aw = sc[j] * inv;
    #pragma unroll
    for (int i = 0; i < 8; ++i) o[i] = fmaf(aw, (float)vr[i], o[i]);
  }
  f16* dst = ao + (size_t)row * EE + h * 64 + sl * 8;
  #pragma unroll
  for (int i = 0; i < 8; ++i) dst[i] = (f16)o[i];
}

extern "C" void kernel_launch(void* const* d_in, const int* in_sizes, int n_in,
                              void* d_out, int out_size, void* d_ws, size_t ws_size,
                              hipStream_t stream) {
  const float* Q    = (const float*)d_in[0];
  const float* mk   = (const float*)d_in[1];
  const float* mv   = (const float*)d_in[2];
  const float* Wq   = (const float*)d_in[3];
  const float* bq   = (const float*)d_in[4];
  const float* Wk   = (const float*)d_in[5];
  const float* bk   = (const float*)d_in[6];
  const float* Wv   = (const float*)d_in[7];
  const float* bv   = (const float*)d_in[8];
  const float* Wiq  = (const float*)d_in[9];
  const float* Wik  = (const float*)d_in[10];
  const float* Wiv  = (const float*)d_in[11];
  const float* b_in = (const float*)d_in[12];
  const float* Wo   = (const float*)d_in[13];
  const float* bo   = (const float*)d_in[14];

  char* w = (char*)d_ws;
  size_t off = 0;
  auto alloc = [&](size_t bytes) { size_t o = off; off += (bytes + 255) & ~(size_t)255; return (void*)(w + o); };
  f16*    Qh     = (f16*)   alloc((size_t)BQ * EE * 2);           // dead after stage1 -> ao
  float*  sq32   = (float*) alloc((size_t)NMEM * 4);
  double* sq64   = (double*)alloc((size_t)NMEM * 8);
  f16*    Wc     = (f16*)   alloc((size_t)3 * EE * EE * 2);
  f16*    Wo16   = (f16*)   alloc((size_t)EE * EE * 2);
  float*  bc     = (float*) alloc((size_t)3 * EE * 4);
  int*    part_i = (int*)   alloc((size_t)BQ * NCAND * 4);
  float*  part_s = (float*) alloc((size_t)BQ * NCAND * 4);
  int*    idx5   = (int*)   alloc((size_t)BQ * 5 * 4);
  f16*    qp     = (f16*)   alloc((size_t)BQ * EE * 2);
  f16*    vp     = (f16*)   alloc((size_t)BQ * 5 * EE * 2);
  f16*    Khf    = (f16*)   alloc((size_t)NSEG * NT32 * TILE_E * 2);   // 51.4MB, dead after stage1
  float*  sqsP   = (float*) alloc((size_t)NSEG * NT32 * KVT * 4);
  f16*    ao     = Qh;
  f16*    kp     = Khf;   // overlay: BQ*5*EE*2 = 41.9MB <= Khf's 51.4MB, Khf dead by then
  // big tier: row-major f16 key/value tables -> gather projections read f16 (half traffic)
  size_t need_big = off + 2 * (size_t)NMEM * EE * 2 + 4096;
  bool big = (ws_size >= need_big);
  f16* Kh = nullptr; f16* Vh = nullptr;
  if (big) {
    Kh = (f16*)alloc((size_t)NMEM * EE * 2);
    Vh = (f16*)alloc((size_t)NMEM * EE * 2);
  }
  (void)in_sizes; (void)n_in; (void)out_size;

  k_prep_keys<<<NMEM / 4, 256, 0, stream>>>(mk, Kh, sq32, sq64);   // Kh may be null
  k_prep_kf<<<dim3(NT32, NSEG), 256, 0, stream>>>(mk, sq32, Khf, sqsP);
  k_prep_f16<<<BQ / 4, 256, 0, stream>>>(Q, Qh);
  if (big) k_prep_f16<<<NMEM / 4, 256, 0, stream>>>(mv, Vh);
  k_compose<<<dim3(8, 8, 3), 256, 0, stream>>>(Wq, Wk, Wv, Wiq, Wik, Wiv, Wc);
  k_bias<<<3, 256, 0, stream>>>(Wiq, Wik, Wiv, bq, bk, bv, b_in, bc);
  k_cvtw<<<(EE * EE) / 256, 256, 0, stream>>>(Wo, Wo16);
  k_stage1<<<dim3(64 * NSEG), 256, 0, stream>>>(Qh, Khf, sqsP, part_i, part_s);
  k_rescore<<<BQ, 64, 0, stream>>>(Q, mk, sq64, part_i, part_s, idx5);
  k_pgemm128<0,1,0><<<dim3(BQ / 128, 8), 256, 0, stream>>>(nullptr, Qh, Wc, bc, qp);
  if (big) {
    k_pgemm128<1,1,0><<<dim3(BQ * 5 / 128, 8), 256, 0, stream>>>(idx5, Kh, Wc + (size_t)EE * EE, bc + EE, kp);
    k_pgemm128<1,1,0><<<dim3(BQ * 5 / 128, 8), 256, 0, stream>>>(idx5, Vh, Wc + (size_t)2 * EE * EE, bc + 2 * EE, vp);
  } else {
    k_pgemm128<1,0,0><<<dim3(BQ * 5 / 128, 8), 256, 0, stream>>>(idx5, mk, Wc + (size_t)EE * EE, bc + EE, kp);
    k_pgemm128<1,0,0><<<dim3(BQ * 5 / 128, 8), 256, 0, stream>>>(idx5, mv, Wc + (size_t)2 * EE * EE, bc + 2 * EE, vp);
  }
  k_attn<<<BQ / 4, 256, 0, stream>>>(qp, kp, vp, ao);
  k_pgemm128<0,1,1><<<dim3(BQ / 128, 8), 256, 0, stream>>>(nullptr, ao, Wo16, bo, d_out);
}

// Round 14
// 738.300 us; speedup vs baseline: 2.0312x; 2.0312x over previous
//
#include <hip/hip_runtime.h>
#include <hip/hip_bf16.h>
#include <hip/hip_fp16.h>

typedef _Float16 f16;
typedef _Float16 f16x8 __attribute__((ext_vector_type(8)));
typedef float f32x4 __attribute__((ext_vector_type(4)));

constexpr int EE     = 512;
constexpr int NMEM   = 50000;
constexpr int BQ     = 8192;
constexpr int NSEG   = 16;
constexpr int SEGLEN = NMEM / NSEG;              // 3125 (exact)
constexpr int KVT    = 32;                       // keys per tile
constexpr int NT32   = (SEGLEN + KVT - 1) / KVT; // 98
constexpr int NC     = 5;                        // candidates kept per segment
constexpr int NCAND  = NSEG * NC;                // 80
constexpr int NRES   = 10;                       // exact-rescored candidates

// generic->addrspace casts for global_load_lds
typedef const __attribute__((address_space(1))) unsigned char* gas_t;
typedef __attribute__((address_space(3))) unsigned char* las_t;
__device__ static inline void g2l16(const void* g, void* l) {
  __builtin_amdgcn_global_load_lds((gas_t)g, (las_t)l, 16, 0, 0);
}

// pack 12-bit local index into low mantissa bits of score (compare-as-float safe:
// perturbation <= 0.125 at |score|~500, far below rank-5..10 gaps; rescore is exact)
__device__ static inline float pack_si(float s, int li) {
  return __uint_as_float((__float_as_uint(s) & 0xFFFFF000u) | (unsigned)li);
}

// ---------------- prep: f32 -> fp16 keys + f64/f32 row norms ----------------
__global__ __launch_bounds__(256) void k_prep_keys(const float* __restrict__ mk,
                                                   f16* __restrict__ kh,
                                                   float* __restrict__ sq32,
                                                   double* __restrict__ sq64) {
  int row  = blockIdx.x * 4 + (threadIdx.x >> 6);
  int lane = threadIdx.x & 63;
  const float4* src = (const float4*)(mk + (size_t)row * EE) + lane * 2;
  float4 a = src[0], b = src[1];
  double s = (double)a.x*a.x + (double)a.y*a.y + (double)a.z*a.z + (double)a.w*a.w
           + (double)b.x*b.x + (double)b.y*b.y + (double)b.z*b.z + (double)b.w*b.w;
  f16x8 h;
  h[0]=(f16)a.x; h[1]=(f16)a.y; h[2]=(f16)a.z; h[3]=(f16)a.w;
  h[4]=(f16)b.x; h[5]=(f16)b.y; h[6]=(f16)b.z; h[7]=(f16)b.w;
  *((f16x8*)(kh + (size_t)row * EE) + lane) = h;
  #pragma unroll
  for (int o = 32; o > 0; o >>= 1) s += __shfl_down(s, o);
  if (lane == 0) { sq64[row] = s; sq32[row] = (float)s; }
}

// generic f32 -> f16 row copy (rows of EE)
__global__ __launch_bounds__(256) void k_prep_f16(const float* __restrict__ src,
                                                  f16* __restrict__ dst) {
  int row  = blockIdx.x * 4 + (threadIdx.x >> 6);
  int lane = threadIdx.x & 63;
  const float4* s = (const float4*)(src + (size_t)row * EE) + lane * 2;
  float4 a = s[0], b = s[1];
  f16x8 h;
  h[0]=(f16)a.x; h[1]=(f16)a.y; h[2]=(f16)a.z; h[3]=(f16)a.w;
  h[4]=(f16)b.x; h[5]=(f16)b.y; h[6]=(f16)b.z; h[7]=(f16)b.w;
  *((f16x8*)(dst + (size_t)row * EE) + lane) = h;
}

// ---------------- compose weights: Wc_m = Win_m @ W_m (f32 acc -> fp16 out) ----------------
__global__ __launch_bounds__(256) void k_compose(const float* __restrict__ Wq, const float* __restrict__ Wk,
                                                 const float* __restrict__ Wv, const float* __restrict__ Wiq,
                                                 const float* __restrict__ Wik, const float* __restrict__ Wiv,
                                                 f16* __restrict__ Wc) {
  int m = blockIdx.z;
  const float* A = (m == 0) ? Wiq : ((m == 1) ? Wik : Wiv);
  const float* B = (m == 0) ? Wq  : ((m == 1) ? Wk  : Wv);
  f16* C = Wc + (size_t)m * EE * EE;
  __shared__ float As[64][33];
  __shared__ float Bs[32][65];
  int i0 = blockIdx.x * 64, j0 = blockIdx.y * 64;
  int tx = threadIdx.x & 15, ty = threadIdx.x >> 4;
  float acc[4][4] = {};
  for (int kb = 0; kb < EE; kb += 32) {
    __syncthreads();
    #pragma unroll
    for (int v = 0; v < 8; ++v) {
      int idx = threadIdx.x + v * 256;
      As[idx >> 5][idx & 31] = A[(size_t)(i0 + (idx >> 5)) * EE + kb + (idx & 31)];
    }
    #pragma unroll
    for (int v = 0; v < 8; ++v) {
      int idx = threadIdx.x + v * 256;
      Bs[idx >> 6][idx & 63] = B[(size_t)(kb + (idx >> 6)) * EE + j0 + (idx & 63)];
    }
    __syncthreads();
    for (int t = 0; t < 32; ++t) {
      float av[4], bv[4];
      #pragma unroll
      for (int u = 0; u < 4; ++u) av[u] = As[ty*4+u][t];
      #pragma unroll
      for (int u = 0; u < 4; ++u) bv[u] = Bs[t][tx*4+u];
      #pragma unroll
      for (int a = 0; a < 4; ++a)
        #pragma unroll
        for (int b = 0; b < 4; ++b) acc[a][b] = fmaf(av[a], bv[b], acc[a][b]);
    }
  }
  #pragma unroll
  for (int a = 0; a < 4; ++a)
    #pragma unroll
    for (int b = 0; b < 4; ++b)
      C[(size_t)(i0 + ty*4 + a) * EE + j0 + tx*4 + b] = (f16)acc[a][b];
}

__global__ void k_bias(const float* __restrict__ Wiq, const float* __restrict__ Wik,
                       const float* __restrict__ Wiv, const float* __restrict__ bqv,
                       const float* __restrict__ bkv, const float* __restrict__ bvv,
                       const float* __restrict__ b_in, float* __restrict__ bc) {
  int m = blockIdx.x;
  const float* Wi = (m == 0) ? Wiq : ((m == 1) ? Wik : Wiv);
  const float* bb = (m == 0) ? bqv : ((m == 1) ? bkv : bvv);
  for (int i = threadIdx.x; i < EE; i += blockDim.x) {
    float s = 0.f;
    for (int t = 0; t < EE; ++t) s = fmaf(Wi[(size_t)i * EE + t], bb[t], s);
    bc[m * EE + i] = s + b_in[m * EE + i];
  }
}

__global__ void k_cvtw(const float* __restrict__ W, f16* __restrict__ Wo) {
  int i = blockIdx.x * 256 + threadIdx.x;
  Wo[i] = (f16)W[i];
}

// ---------------- stage 1: swapped-operand fp16 MFMA scores, packed register top-5 ----------------
__global__ __launch_bounds__(256, 2) void k_stage1(const f16* __restrict__ Qh,
                                                   const f16* __restrict__ Kh,
                                                   const float* __restrict__ sq32,
                                                   int* __restrict__ part_i,
                                                   float* __restrict__ part_s) {
  const int rb  = blockIdx.x;        // 0..63 (128 rows each)
  const int seg = blockIdx.y;        // 0..15
  const int tid = threadIdx.x;
  const int w   = tid >> 6;          // wave 0..3
  const int l   = tid & 63;
  const int lc  = l & 15, lp = l >> 4;
  const int seg_start = seg * SEGLEN;
  const int seg_end   = seg_start + SEGLEN;

  __shared__ f16   Bt[2][KVT * 520];
  __shared__ float sqs[2][KVT];

  const int rowbase = rb * 128 + w * 32;
  f16x8 a0[16], a1[16];
  {
    const f16* base0 = Qh + (size_t)(rowbase + lc) * EE + lp * 8;
    const f16* base1 = base0 + (size_t)16 * EE;
    #pragma unroll
    for (int ks = 0; ks < 16; ++ks) {
      asm volatile("global_load_dwordx4 %0, %1, off"
                   : "=v"(a0[ks]) : "v"(base0 + ks * 32) : "memory");
      asm volatile("global_load_dwordx4 %0, %1, off"
                   : "=v"(a1[ks]) : "v"(base1 + ks * 32) : "memory");
    }
    asm volatile("s_waitcnt vmcnt(0)" ::: "memory");
    __builtin_amdgcn_sched_barrier(0);
  }

  // packed lists: ts0 -> qrow rowbase+lc, ts1 -> qrow rowbase+16+lc (key-striped by lp)
  float ts0[NC], ts1[NC];
  #pragma unroll
  for (int i = 0; i < NC; ++i) { ts0[i] = -3.0e38f; ts1[i] = -3.0e38f; }

// unguarded sorted insert: entry-max + 4-level fmax/fmin bubble (idempotent when
// PV doesn't qualify). Ballot guard removed: hit-rate analysis shows the wave-level
// branch is taken on ~every tile (1-(1-5/t)^128 ~ 1 for t<=98), so it was pure cost.
#define INS1(TS, PV) do { \
    TS[NC-1] = fmaxf(TS[NC-1], (PV)); \
    _Pragma("unroll") \
    for (int _i = NC - 1; _i > 0; --_i) { \
      float _mx = fmaxf(TS[_i], TS[_i-1]); \
      float _mn = fminf(TS[_i], TS[_i-1]); \
      TS[_i-1] = _mx; TS[_i] = _mn; \
    } \
  } while (0)

  // stage tile tt into buffer buf: 8 rows per wave, direct global->LDS
  #define STAGE(buf, tt) do { \
      int kk = seg_start + (tt) * KVT; \
      _Pragma("unroll") \
      for (int j = 0; j < 8; ++j) { \
        int key = kk + w * 8 + j; \
        key = key < NMEM ? key : NMEM - 1; \
        g2l16(Kh + (size_t)key * EE + l * 8, &Bt[buf][(w*8 + j) * 520]); \
      } \
      if (tid < KVT) { \
        int kq = kk + tid; \
        float v = 6.0e38f; \
        if (kq < seg_end) v = sq32[kq]; \
        sqs[buf][tid] = v; \
      } \
    } while (0)

  STAGE(0, 0);
  for (int t = 0; t < NT32; ++t) {
    const int c = t & 1;
    __syncthreads();               // drains vmcnt: buf[c] staged; prior reads of buf[c^1] done
    if (t + 1 < NT32) STAGE(c ^ 1, t + 1);   // in-flight during compute; drained at next barrier

    f32x4 A00 = {0,0,0,0}, A01 = {0,0,0,0}, A10 = {0,0,0,0}, A11 = {0,0,0,0};
    #pragma unroll
    for (int ks = 0; ks < 16; ++ks) {
      f16x8 kf0 = *(const f16x8*)&Bt[c][lc * 520 + ks * 32 + lp * 8];
      f16x8 kf1 = *(const f16x8*)&Bt[c][(16 + lc) * 520 + ks * 32 + lp * 8];
      A00 = __builtin_amdgcn_mfma_f32_16x16x32_f16(kf0, a0[ks], A00, 0, 0, 0);
      A01 = __builtin_amdgcn_mfma_f32_16x16x32_f16(kf0, a1[ks], A01, 0, 0, 0);
      A10 = __builtin_amdgcn_mfma_f32_16x16x32_f16(kf1, a0[ks], A10, 0, 0, 0);
      A11 = __builtin_amdgcn_mfma_f32_16x16x32_f16(kf1, a1[ks], A11, 0, 0, 0);
    }
    // epilogue: vector scores (poisoned sqs makes OOB keys -6e38), packed inserts
    f32x4 q0 = *(const f32x4*)&sqs[c][lp * 4];
    f32x4 q1 = *(const f32x4*)&sqs[c][16 + lp * 4];
    f32x4 s00 = 2.0f * A00 - q0;
    f32x4 s01 = 2.0f * A01 - q0;
    f32x4 s10 = 2.0f * A10 - q1;
    f32x4 s11 = 2.0f * A11 - q1;
    const int li0 = t * KVT + lp * 4;   // 12-bit local key index (<= 3135)
    const int li1 = li0 + 16;
    #pragma unroll
    for (int r = 0; r < 4; ++r) {
      INS1(ts0, pack_si(s00[r], li0 + r));
      INS1(ts0, pack_si(s10[r], li1 + r));
      INS1(ts1, pack_si(s01[r], li0 + r));
      INS1(ts1, pack_si(s11[r], li1 + r));
    }
  }
  #undef STAGE

  // merge key-stripes: lanes {lc, lc+16, lc+32, lc+48} hold disjoint stripes of same q-rows
  #pragma unroll
  for (int d = 16; d <= 32; d <<= 1) {
    float os[NC];
    #pragma unroll
    for (int i = 0; i < NC; ++i) os[i] = __shfl_xor(ts0[i], d);
    #pragma unroll
    for (int j = 0; j < NC; ++j) INS1(ts0, os[j]);
    #pragma unroll
    for (int i = 0; i < NC; ++i) os[i] = __shfl_xor(ts1[i], d);
    #pragma unroll
    for (int j = 0; j < NC; ++j) INS1(ts1, os[j]);
  }
#undef INS1
  if (l < 16) {
    int row = rowbase + lc;
    #pragma unroll
    for (int i = 0; i < NC; ++i) {
      unsigned u = __float_as_uint(ts0[i]);
      part_i[(size_t)row * NCAND + seg * NC + i] = seg_start + (int)(u & 0xFFFu);
      part_s[(size_t)row * NCAND + seg * NC + i] = ts0[i];
    }
  } else if (l < 32) {
    int row = rowbase + 16 + lc;
    #pragma unroll
    for (int i = 0; i < NC; ++i) {
      unsigned u = __float_as_uint(ts1[i]);
      part_i[(size_t)row * NCAND + seg * NC + i] = seg_start + (int)(u & 0xFFFu);
      part_s[(size_t)row * NCAND + seg * NC + i] = ts1[i];
    }
  }
}

// ---------------- stage 2: noisy top-10 of 80, exact f64 rescore -> top-5 ----------------
__global__ __launch_bounds__(64) void k_rescore(const float* __restrict__ Q,
                                                const float* __restrict__ mk,
                                                const double* __restrict__ sq64,
                                                const int* __restrict__ part_i,
                                                const float* __restrict__ part_s,
                                                int* __restrict__ idx5) {
  const int row = blockIdx.x;
  const int l = threadIdx.x;
  const float* Qr = Q + (size_t)row * EE;
  float q[8];
  #pragma unroll
  for (int i = 0; i < 8; ++i) q[i] = Qr[l + 64*i];
  float s0 = part_s[(size_t)row * NCAND + l];
  int   i0 = part_i[(size_t)row * NCAND + l];
  float s1 = (l < NCAND - 64) ? part_s[(size_t)row * NCAND + 64 + l] : -3.0e38f;
  int   i1 = (l < NCAND - 64) ? part_i[(size_t)row * NCAND + 64 + l] : 0;

  double bs[5] = {-1e300, -1e300, -1e300, -1e300, -1e300};
  int    bi[5] = {0, 0, 0, 0, 0};
  #pragma unroll
  for (int p = 0; p < NRES; ++p) {
    bool pick0 = (s0 >= s1);
    float m  = pick0 ? s0 : s1;
    int   mi = pick0 ? i0 : i1;
    int   code = (l << 1) | (pick0 ? 0 : 1);
    #pragma unroll
    for (int o = 32; o > 0; o >>= 1) {
      float mo = __shfl_xor(m, o);
      int   io = __shfl_xor(mi, o);
      int   co = __shfl_xor(code, o);
      if (mo > m || (mo == m && co < code)) { m = mo; mi = io; code = co; }
    }
    if ((code >> 1) == l) { if (code & 1) s1 = -3.0e38f; else s0 = -3.0e38f; }
    const float* kr = mk + (size_t)mi * EE;
    double pd = 0.0;
    #pragma unroll
    for (int i = 0; i < 8; ++i) pd += (double)q[i] * (double)kr[l + 64*i];
    #pragma unroll
    for (int o = 32; o > 0; o >>= 1) pd += __shfl_down(pd, o);
    if (l == 0) {
      double s = 2.0 * pd - sq64[mi];
      if (s > bs[4]) {
        bs[4] = s; bi[4] = mi;
        #pragma unroll
        for (int i = 4; i > 0; --i) {
          if (bs[i] > bs[i-1]) {
            double tf = bs[i]; bs[i] = bs[i-1]; bs[i-1] = tf;
            int    tx = bi[i]; bi[i] = bi[i-1]; bi[i-1] = tx;
          }
        }
      }
    }
  }
  if (l == 0) {
    #pragma unroll
    for (int i = 0; i < 5; ++i) idx5[(size_t)row*5 + i] = bi[i];
  }
}

// ---------------- unified 128x64-tile fp16 MFMA GEMM: C = A(rows) @ B^T + bias ----------------
template <int GATHER, int AF16, int OUTF32>
__global__ __launch_bounds__(256) void k_pgemm128(const int* __restrict__ gidx, const void* __restrict__ Asrc,
                                                  const f16* __restrict__ B, const float* __restrict__ bias,
                                                  void* __restrict__ outp) {
  __shared__ f16 As[128][72];
  __shared__ f16 Bs[64][72];
  const int tid = threadIdx.x;
  const int wv = tid >> 6, l = tid & 63, lc = l & 15, lp = l >> 4;
  const int m0 = blockIdx.x * 128, n0 = blockIdx.y * 64;
  const int r0 = tid >> 3;
  const int cb = (tid & 7) * 8;
  const f16*   arf[4];
  const float* ar32[4];
  #pragma unroll
  for (int v = 0; v < 4; ++v) {
    int row = m0 + r0 + v * 32;
    int gi = GATHER ? gidx[row] : row;
    if (AF16) arf[v]  = (const f16*)Asrc + (size_t)gi * EE;
    else      ar32[v] = (const float*)Asrc + (size_t)gi * EE;
  }
  const f16* br0 = B + (size_t)(n0 + r0) * EE;
  const f16* br1 = B + (size_t)(n0 + r0 + 32) * EE;
  f32x4 acc[2][4] = {{{0,0,0,0},{0,0,0,0},{0,0,0,0},{0,0,0,0}},
                     {{0,0,0,0},{0,0,0,0},{0,0,0,0},{0,0,0,0}}};
  for (int kb = 0; kb < EE; kb += 64) {
    __syncthreads();
    #pragma unroll
    for (int v = 0; v < 4; ++v) {
      if (AF16) {
        *(f16x8*)&As[r0 + v*32][cb] = *(const f16x8*)(arf[v] + kb + cb);
      } else {
        float4 x0 = *(const float4*)(ar32[v] + kb + cb);
        float4 x1 = *(const float4*)(ar32[v] + kb + cb + 4);
        f16x8 h;
        h[0]=(f16)x0.x; h[1]=(f16)x0.y; h[2]=(f16)x0.z; h[3]=(f16)x0.w;
        h[4]=(f16)x1.x; h[5]=(f16)x1.y; h[6]=(f16)x1.z; h[7]=(f16)x1.w;
        *(f16x8*)&As[r0 + v*32][cb] = h;
      }
    }
    *(f16x8*)&Bs[r0][cb]      = *(const f16x8*)(br0 + kb + cb);
    *(f16x8*)&Bs[r0 + 32][cb] = *(const f16x8*)(br1 + kb + cb);
    __syncthreads();
    #pragma unroll
    for (int ks = 0; ks < 2; ++ks) {
      f16x8 a0 = *(const f16x8*)&As[wv*32 + lc][ks*32 + lp*8];
      f16x8 a1 = *(const f16x8*)&As[wv*32 + 16 + lc][ks*32 + lp*8];
      #pragma unroll
      for (int f = 0; f < 4; ++f) {
        f16x8 b = *(const f16x8*)&Bs[f*16 + lc][ks*32 + lp*8];
        acc[0][f] = __builtin_amdgcn_mfma_f32_16x16x32_f16(a0, b, acc[0][f], 0, 0, 0);
        acc[1][f] = __builtin_amdgcn_mfma_f32_16x16x32_f16(a1, b, acc[1][f], 0, 0, 0);
      }
    }
  }
  #pragma unroll
  for (int g = 0; g < 2; ++g) {
    #pragma unroll
    for (int f = 0; f < 4; ++f) {
      int col = n0 + f*16 + lc;
      float bsv = bias[col];
      #pragma unroll
      for (int rr = 0; rr < 4; ++rr) {
        int row = m0 + wv*32 + g*16 + lp*4 + rr;
        float v = acc[g][f][rr] + bsv;
        if (OUTF32) ((float*)outp)[(size_t)row * EE + col] = v;
        else        ((f16*)outp)[(size_t)row * EE + col] = (f16)v;
      }
    }
  }
}

// ---------------- 5-key MHA (H=8, d=64), f32 compute ----------------
__global__ __launch_bounds__(256) void k_attn(const f16* __restrict__ qp, const f16* __restrict__ kp,
                                              const f16* __restrict__ vp, f16* __restrict__ ao) {
  int row = blockIdx.x * 4 + (threadIdx.x >> 6);
  int l = threadIdx.x & 63;
  int h = l >> 3, sl = l & 7;
  const f16* q = qp + (size_t)row * EE + h * 64 + sl * 8;
  float qv[8];
  #pragma unroll
  for (int i = 0; i < 8; ++i) qv[i] = (float)q[i];
  float sc[5];
  #pragma unroll
  for (int j = 0; j < 5; ++j) {
    const f16* kr = kp + ((size_t)row * 5 + j) * EE + h * 64 + sl * 8;
    float p = 0.f;
    #pragma unroll
    for (int i = 0; i < 8; ++i) p = fmaf(qv[i], (float)kr[i], p);
    p += __shfl_xor(p, 1); p += __shfl_xor(p, 2); p += __shfl_xor(p, 4);
    sc[j] = p * 0.125f;
  }
  float mx = fmaxf(fmaxf(fmaxf(sc[0], sc[1]), fmaxf(sc[2], sc[3])), sc[4]);
  float sum = 0.f;
  #pragma unroll
  for (int j = 0; j < 5; ++j) { sc[j] = __expf(sc[j] - mx); sum += sc[j]; }
  float inv = 1.0f / sum;
  float o[8] = {};
  #pragma unroll
  for (int j = 0; j < 5; ++j) {
    const f16* vr = vp + ((size_t)row * 5 + j) * EE + h * 64 + sl * 8;
    float aw = sc[j] * inv;
    #pragma unroll
    for (int i = 0; i < 8; ++i) o[i] = fmaf(aw, (float)vr[i], o[i]);
  }
  f16* dst = ao + (size_t)row * EE + h * 64 + sl * 8;
  #pragma unroll
  for (int i = 0; i < 8; ++i) dst[i] = (f16)o[i];
}

extern "C" void kernel_launch(void* const* d_in, const int* in_sizes, int n_in,
                              void* d_out, int out_size, void* d_ws, size_t ws_size,
                              hipStream_t stream) {
  const float* Q    = (const float*)d_in[0];
  const float* mk   = (const float*)d_in[1];
  const float* mv   = (const float*)d_in[2];
  const float* Wq   = (const float*)d_in[3];
  const float* bq   = (const float*)d_in[4];
  const float* Wk   = (const float*)d_in[5];
  const float* bk   = (const float*)d_in[6];
  const float* Wv   = (const float*)d_in[7];
  const float* bv   = (const float*)d_in[8];
  const float* Wiq  = (const float*)d_in[9];
  const float* Wik  = (const float*)d_in[10];
  const float* Wiv  = (const float*)d_in[11];
  const float* b_in = (const float*)d_in[12];
  const float* Wo   = (const float*)d_in[13];
  const float* bo   = (const float*)d_in[14];

  char* w = (char*)d_ws;
  size_t off = 0;
  auto alloc = [&](size_t bytes) { size_t o = off; off += (bytes + 255) & ~(size_t)255; return (void*)(w + o); };
  f16*    Kh     = (f16*)   alloc((size_t)NMEM * EE * 2);
  f16*    Qh     = (f16*)   alloc((size_t)BQ * EE * 2);   // dead after stage1 -> ao
  float*  sq32   = (float*) alloc((size_t)NMEM * 4);
  double* sq64   = (double*)alloc((size_t)NMEM * 8);
  f16*    Wc     = (f16*)   alloc((size_t)3 * EE * EE * 2);
  f16*    Wo16   = (f16*)   alloc((size_t)EE * EE * 2);
  float*  bc     = (float*) alloc((size_t)3 * EE * 4);
  int*    part_i = (int*)   alloc((size_t)BQ * NCAND * 4);
  float*  part_s = (float*) alloc((size_t)BQ * NCAND * 4);
  int*    idx5   = (int*)   alloc((size_t)BQ * 5 * 4);
  f16*    qp     = (f16*)   alloc((size_t)BQ * EE * 2);
  f16*    vp     = (f16*)   alloc((size_t)BQ * 5 * EE * 2);
  f16*    ao     = Qh;
  // big tier: separate kp + f16 value table -> gather projections read f16 (half traffic)
  size_t need_big = off + (size_t)NMEM * EE * 2 + (size_t)BQ * 5 * EE * 2 + 4096;
  bool big = (ws_size >= need_big);
  f16* Vh = nullptr;
  f16* kp;
  if (big) {
    Vh = (f16*)alloc((size_t)NMEM * EE * 2);
    kp = (f16*)alloc((size_t)BQ * 5 * EE * 2);
  } else {
    kp = Kh;   // overlay: Kh dead after stage1 in small tier
  }
  (void)in_sizes; (void)n_in; (void)out_size;

  k_prep_keys<<<NMEM / 4, 256, 0, stream>>>(mk, Kh, sq32, sq64);
  k_prep_f16<<<BQ / 4, 256, 0, stream>>>(Q, Qh);
  if (big) k_prep_f16<<<NMEM / 4, 256, 0, stream>>>(mv, Vh);
  k_compose<<<dim3(8, 8, 3), 256, 0, stream>>>(Wq, Wk, Wv, Wiq, Wik, Wiv, Wc);
  k_bias<<<3, 256, 0, stream>>>(Wiq, Wik, Wiv, bq, bk, bv, b_in, bc);
  k_cvtw<<<(EE * EE) / 256, 256, 0, stream>>>(Wo, Wo16);
  k_stage1<<<dim3(BQ / 128, NSEG), 256, 0, stream>>>(Qh, Kh, sq32, part_i, part_s);
  k_rescore<<<BQ, 64, 0, stream>>>(Q, mk, sq64, part_i, part_s, idx5);
  k_pgemm128<0,1,0><<<dim3(BQ / 128, 8), 256, 0, stream>>>(nullptr, Qh, Wc, bc, qp);
  if (big) {
    k_pgemm128<1,1,0><<<dim3(BQ * 5 / 128, 8), 256, 0, stream>>>(idx5, Kh, Wc + (size_t)EE * EE, bc + EE, kp);
    k_pgemm128<1,1,0><<<dim3(BQ * 5 / 128, 8), 256, 0, stream>>>(idx5, Vh, Wc + (size_t)2 * EE * EE, bc + 2 * EE, vp);
  } else {
    k_pgemm128<1,0,0><<<dim3(BQ * 5 / 128, 8), 256, 0, stream>>>(idx5, mk, Wc + (size_t)EE * EE, bc + EE, kp);
    k_pgemm128<1,0,0><<<dim3(BQ * 5 / 128, 8), 256, 0, stream>>>(idx5, mv, Wc + (size_t)2 * EE * EE, bc + 2 * EE, vp);
  }
  k_attn<<<BQ / 4, 256, 0, stream>>>(qp, kp, vp, ao);
  k_pgemm128<0,1,1><<<dim3(BQ / 128, 8), 256, 0, stream>>>(nullptr, ao, Wo16, bo, d_out);
}

// Round 15
// 727.002 us; speedup vs baseline: 2.0628x; 1.0155x over previous
//
#include <hip/hip_runtime.h>
#include <hip/hip_bf16.h>
#include <hip/hip_fp16.h>

typedef _Float16 f16;
typedef _Float16 f16x8 __attribute__((ext_vector_type(8)));
typedef float f32x4 __attribute__((ext_vector_type(4)));

constexpr int EE     = 512;
constexpr int NMEM   = 50000;
constexpr int BQ     = 8192;
constexpr int NSEG   = 16;
constexpr int SEGLEN = NMEM / NSEG;              // 3125 (exact)
constexpr int KVT    = 32;                       // keys per tile
constexpr int NT32   = (SEGLEN + KVT - 1) / KVT; // 98
constexpr int NC     = 5;                        // candidates kept per segment
constexpr int NCAND  = NSEG * NC;                // 80
constexpr int NRES   = 10;                       // exact-rescored candidates

// generic->addrspace casts for global_load_lds
typedef const __attribute__((address_space(1))) unsigned char* gas_t;
typedef __attribute__((address_space(3))) unsigned char* las_t;
__device__ static inline void g2l16(const void* g, void* l) {
  __builtin_amdgcn_global_load_lds((gas_t)g, (las_t)l, 16, 0, 0);
}

// pack 12-bit local index into low mantissa bits of score (compare-as-float safe:
// perturbation <= 0.125 at |score|~500, far below rank-5..10 gaps; rescore is exact)
__device__ static inline float pack_si(float s, int li) {
  return __uint_as_float((__float_as_uint(s) & 0xFFFFF000u) | (unsigned)li);
}

// ---------------- prep: f32 -> fp16 keys + f64/f32 row norms ----------------
__global__ __launch_bounds__(256) void k_prep_keys(const float* __restrict__ mk,
                                                   f16* __restrict__ kh,
                                                   float* __restrict__ sq32,
                                                   double* __restrict__ sq64) {
  int row  = blockIdx.x * 4 + (threadIdx.x >> 6);
  int lane = threadIdx.x & 63;
  const float4* src = (const float4*)(mk + (size_t)row * EE) + lane * 2;
  float4 a = src[0], b = src[1];
  double s = (double)a.x*a.x + (double)a.y*a.y + (double)a.z*a.z + (double)a.w*a.w
           + (double)b.x*b.x + (double)b.y*b.y + (double)b.z*b.z + (double)b.w*b.w;
  f16x8 h;
  h[0]=(f16)a.x; h[1]=(f16)a.y; h[2]=(f16)a.z; h[3]=(f16)a.w;
  h[4]=(f16)b.x; h[5]=(f16)b.y; h[6]=(f16)b.z; h[7]=(f16)b.w;
  *((f16x8*)(kh + (size_t)row * EE) + lane) = h;
  #pragma unroll
  for (int o = 32; o > 0; o >>= 1) s += __shfl_down(s, o);
  if (lane == 0) { sq64[row] = s; sq32[row] = (float)s; }
}

// generic f32 -> f16 row copy (rows of EE)
__global__ __launch_bounds__(256) void k_prep_f16(const float* __restrict__ src,
                                                  f16* __restrict__ dst) {
  int row  = blockIdx.x * 4 + (threadIdx.x >> 6);
  int lane = threadIdx.x & 63;
  const float4* s = (const float4*)(src + (size_t)row * EE) + lane * 2;
  float4 a = s[0], b = s[1];
  f16x8 h;
  h[0]=(f16)a.x; h[1]=(f16)a.y; h[2]=(f16)a.z; h[3]=(f16)a.w;
  h[4]=(f16)b.x; h[5]=(f16)b.y; h[6]=(f16)b.z; h[7]=(f16)b.w;
  *((f16x8*)(dst + (size_t)row * EE) + lane) = h;
}

// ---------------- compose weights: Wc_m = Win_m @ W_m (f32 acc -> fp16 out) ----------------
__global__ __launch_bounds__(256) void k_compose(const float* __restrict__ Wq, const float* __restrict__ Wk,
                                                 const float* __restrict__ Wv, const float* __restrict__ Wiq,
                                                 const float* __restrict__ Wik, const float* __restrict__ Wiv,
                                                 f16* __restrict__ Wc) {
  int m = blockIdx.z;
  const float* A = (m == 0) ? Wiq : ((m == 1) ? Wik : Wiv);
  const float* B = (m == 0) ? Wq  : ((m == 1) ? Wk  : Wv);
  f16* C = Wc + (size_t)m * EE * EE;
  __shared__ float As[64][33];
  __shared__ float Bs[32][65];
  int i0 = blockIdx.x * 64, j0 = blockIdx.y * 64;
  int tx = threadIdx.x & 15, ty = threadIdx.x >> 4;
  float acc[4][4] = {};
  for (int kb = 0; kb < EE; kb += 32) {
    __syncthreads();
    #pragma unroll
    for (int v = 0; v < 8; ++v) {
      int idx = threadIdx.x + v * 256;
      As[idx >> 5][idx & 31] = A[(size_t)(i0 + (idx >> 5)) * EE + kb + (idx & 31)];
    }
    #pragma unroll
    for (int v = 0; v < 8; ++v) {
      int idx = threadIdx.x + v * 256;
      Bs[idx >> 6][idx & 63] = B[(size_t)(kb + (idx >> 6)) * EE + j0 + (idx & 63)];
    }
    __syncthreads();
    for (int t = 0; t < 32; ++t) {
      float av[4], bv[4];
      #pragma unroll
      for (int u = 0; u < 4; ++u) av[u] = As[ty*4+u][t];
      #pragma unroll
      for (int u = 0; u < 4; ++u) bv[u] = Bs[t][tx*4+u];
      #pragma unroll
      for (int a = 0; a < 4; ++a)
        #pragma unroll
        for (int b = 0; b < 4; ++b) acc[a][b] = fmaf(av[a], bv[b], acc[a][b]);
    }
  }
  #pragma unroll
  for (int a = 0; a < 4; ++a)
    #pragma unroll
    for (int b = 0; b < 4; ++b)
      C[(size_t)(i0 + ty*4 + a) * EE + j0 + tx*4 + b] = (f16)acc[a][b];
}

__global__ void k_bias(const float* __restrict__ Wiq, const float* __restrict__ Wik,
                       const float* __restrict__ Wiv, const float* __restrict__ bqv,
                       const float* __restrict__ bkv, const float* __restrict__ bvv,
                       const float* __restrict__ b_in, float* __restrict__ bc) {
  int m = blockIdx.x;
  const float* Wi = (m == 0) ? Wiq : ((m == 1) ? Wik : Wiv);
  const float* bb = (m == 0) ? bqv : ((m == 1) ? bkv : bvv);
  for (int i = threadIdx.x; i < EE; i += blockDim.x) {
    float s = 0.f;
    for (int t = 0; t < EE; ++t) s = fmaf(Wi[(size_t)i * EE + t], bb[t], s);
    bc[m * EE + i] = s + b_in[m * EE + i];
  }
}

__global__ void k_cvtw(const float* __restrict__ W, f16* __restrict__ Wo) {
  int i = blockIdx.x * 256 + threadIdx.x;
  Wo[i] = (f16)W[i];
}

// ---------------- stage 1: swapped-operand fp16 MFMA scores, deferred register top-5 ----------------
// Selection of tile t-1 runs at the top of iteration t (independent of tile t's
// ds_read+MFMA stream) so the serial insert chain hides under the matrix pipe.
__global__ __launch_bounds__(256, 2) void k_stage1(const f16* __restrict__ Qh,
                                                   const f16* __restrict__ Kh,
                                                   const float* __restrict__ sq32,
                                                   int* __restrict__ part_i,
                                                   float* __restrict__ part_s) {
  const int rb  = blockIdx.x;        // 0..63 (128 rows each)
  const int seg = blockIdx.y;        // 0..15
  const int tid = threadIdx.x;
  const int w   = tid >> 6;          // wave 0..3
  const int l   = tid & 63;
  const int lc  = l & 15, lp = l >> 4;
  const int seg_start = seg * SEGLEN;
  const int seg_end   = seg_start + SEGLEN;

  __shared__ f16   Bt[2][KVT * 520];
  __shared__ float sqs[2][KVT];

  const int rowbase = rb * 128 + w * 32;
  f16x8 a0[16], a1[16];
  {
    const f16* base0 = Qh + (size_t)(rowbase + lc) * EE + lp * 8;
    const f16* base1 = base0 + (size_t)16 * EE;
    #pragma unroll
    for (int ks = 0; ks < 16; ++ks) {
      asm volatile("global_load_dwordx4 %0, %1, off"
                   : "=v"(a0[ks]) : "v"(base0 + ks * 32) : "memory");
      asm volatile("global_load_dwordx4 %0, %1, off"
                   : "=v"(a1[ks]) : "v"(base1 + ks * 32) : "memory");
    }
    asm volatile("s_waitcnt vmcnt(0)" ::: "memory");
    __builtin_amdgcn_sched_barrier(0);
  }

  // packed lists: ts0 -> qrow rowbase+lc, ts1 -> qrow rowbase+16+lc (key-striped by lp)
  float ts0[NC], ts1[NC];
  #pragma unroll
  for (int i = 0; i < NC; ++i) { ts0[i] = -3.0e38f; ts1[i] = -3.0e38f; }
  // saved packed scores of the previous tile (selection deferred one tile)
  float sv0[8], sv1[8];
  #pragma unroll
  for (int i = 0; i < 8; ++i) { sv0[i] = -3.0e38f; sv1[i] = -3.0e38f; }

// unguarded sorted insert: entry-max + 4-level fmax/fmin bubble (idempotent when
// PV doesn't qualify; sentinel -3e38 inserts are no-ops).
#define INS1(TS, PV) do { \
    TS[NC-1] = fmaxf(TS[NC-1], (PV)); \
    _Pragma("unroll") \
    for (int _i = NC - 1; _i > 0; --_i) { \
      float _mx = fmaxf(TS[_i], TS[_i-1]); \
      float _mn = fminf(TS[_i], TS[_i-1]); \
      TS[_i-1] = _mx; TS[_i] = _mn; \
    } \
  } while (0)

  // stage tile tt into buffer buf: 8 rows per wave, direct global->LDS
  #define STAGE(buf, tt) do { \
      int kk = seg_start + (tt) * KVT; \
      _Pragma("unroll") \
      for (int j = 0; j < 8; ++j) { \
        int key = kk + w * 8 + j; \
        key = key < NMEM ? key : NMEM - 1; \
        g2l16(Kh + (size_t)key * EE + l * 8, &Bt[buf][(w*8 + j) * 520]); \
      } \
      if (tid < KVT) { \
        int kq = kk + tid; \
        float v = 6.0e38f; \
        if (kq < seg_end) v = sq32[kq]; \
        sqs[buf][tid] = v; \
      } \
    } while (0)

  STAGE(0, 0);
  for (int t = 0; t < NT32; ++t) {
    const int c = t & 1;
    __syncthreads();               // drains vmcnt: buf[c] staged; prior reads of buf[c^1] done
    if (t + 1 < NT32) STAGE(c ^ 1, t + 1);   // in-flight during compute; drained at next barrier

    // deferred selection of tile t-1: independent of this tile's ds_read/MFMA stream,
    // so the scheduler interleaves the serial insert chain under the matrix pipe.
    #pragma unroll
    for (int r = 0; r < 8; ++r) { INS1(ts0, sv0[r]); INS1(ts1, sv1[r]); }

    f32x4 A00 = {0,0,0,0}, A01 = {0,0,0,0}, A10 = {0,0,0,0}, A11 = {0,0,0,0};
    #pragma unroll
    for (int ks = 0; ks < 16; ++ks) {
      f16x8 kf0 = *(const f16x8*)&Bt[c][lc * 520 + ks * 32 + lp * 8];
      f16x8 kf1 = *(const f16x8*)&Bt[c][(16 + lc) * 520 + ks * 32 + lp * 8];
      A00 = __builtin_amdgcn_mfma_f32_16x16x32_f16(kf0, a0[ks], A00, 0, 0, 0);
      A01 = __builtin_amdgcn_mfma_f32_16x16x32_f16(kf0, a1[ks], A01, 0, 0, 0);
      A10 = __builtin_amdgcn_mfma_f32_16x16x32_f16(kf1, a0[ks], A10, 0, 0, 0);
      A11 = __builtin_amdgcn_mfma_f32_16x16x32_f16(kf1, a1[ks], A11, 0, 0, 0);
    }
    // compute + pack this tile's scores into sv (consumed at iteration t+1)
    f32x4 q0 = *(const f32x4*)&sqs[c][lp * 4];
    f32x4 q1 = *(const f32x4*)&sqs[c][16 + lp * 4];
    f32x4 s00 = 2.0f * A00 - q0;
    f32x4 s01 = 2.0f * A01 - q0;
    f32x4 s10 = 2.0f * A10 - q1;
    f32x4 s11 = 2.0f * A11 - q1;
    const int li0 = t * KVT + lp * 4;   // 12-bit local key index (<= 3135)
    const int li1 = li0 + 16;
    #pragma unroll
    for (int r = 0; r < 4; ++r) {
      sv0[r]     = pack_si(s00[r], li0 + r);
      sv0[r + 4] = pack_si(s10[r], li1 + r);
      sv1[r]     = pack_si(s01[r], li0 + r);
      sv1[r + 4] = pack_si(s11[r], li1 + r);
    }
  }
  #undef STAGE
  // epilogue: flush last tile's deferred selection
  #pragma unroll
  for (int r = 0; r < 8; ++r) { INS1(ts0, sv0[r]); INS1(ts1, sv1[r]); }

  // merge key-stripes: lanes {lc, lc+16, lc+32, lc+48} hold disjoint stripes of same q-rows
  #pragma unroll
  for (int d = 16; d <= 32; d <<= 1) {
    float os[NC];
    #pragma unroll
    for (int i = 0; i < NC; ++i) os[i] = __shfl_xor(ts0[i], d);
    #pragma unroll
    for (int j = 0; j < NC; ++j) INS1(ts0, os[j]);
    #pragma unroll
    for (int i = 0; i < NC; ++i) os[i] = __shfl_xor(ts1[i], d);
    #pragma unroll
    for (int j = 0; j < NC; ++j) INS1(ts1, os[j]);
  }
#undef INS1
  if (l < 16) {
    int row = rowbase + lc;
    #pragma unroll
    for (int i = 0; i < NC; ++i) {
      unsigned u = __float_as_uint(ts0[i]);
      part_i[(size_t)row * NCAND + seg * NC + i] = seg_start + (int)(u & 0xFFFu);
      part_s[(size_t)row * NCAND + seg * NC + i] = ts0[i];
    }
  } else if (l < 32) {
    int row = rowbase + 16 + lc;
    #pragma unroll
    for (int i = 0; i < NC; ++i) {
      unsigned u = __float_as_uint(ts1[i]);
      part_i[(size_t)row * NCAND + seg * NC + i] = seg_start + (int)(u & 0xFFFu);
      part_s[(size_t)row * NCAND + seg * NC + i] = ts1[i];
    }
  }
}

// ---------------- stage 2: noisy top-10 of 80, exact f64 rescore -> top-5 ----------------
__global__ __launch_bounds__(64) void k_rescore(const float* __restrict__ Q,
                                                const float* __restrict__ mk,
                                                const double* __restrict__ sq64,
                                                const int* __restrict__ part_i,
                                                const float* __restrict__ part_s,
                                                int* __restrict__ idx5) {
  const int row = blockIdx.x;
  const int l = threadIdx.x;
  const float* Qr = Q + (size_t)row * EE;
  float q[8];
  #pragma unroll
  for (int i = 0; i < 8; ++i) q[i] = Qr[l + 64*i];
  float s0 = part_s[(size_t)row * NCAND + l];
  int   i0 = part_i[(size_t)row * NCAND + l];
  float s1 = (l < NCAND - 64) ? part_s[(size_t)row * NCAND + 64 + l] : -3.0e38f;
  int   i1 = (l < NCAND - 64) ? part_i[(size_t)row * NCAND + 64 + l] : 0;

  double bs[5] = {-1e300, -1e300, -1e300, -1e300, -1e300};
  int    bi[5] = {0, 0, 0, 0, 0};
  #pragma unroll
  for (int p = 0; p < NRES; ++p) {
    bool pick0 = (s0 >= s1);
    float m  = pick0 ? s0 : s1;
    int   mi = pick0 ? i0 : i1;
    int   code = (l << 1) | (pick0 ? 0 : 1);
    #pragma unroll
    for (int o = 32; o > 0; o >>= 1) {
      float mo = __shfl_xor(m, o);
      int   io = __shfl_xor(mi, o);
      int   co = __shfl_xor(code, o);
      if (mo > m || (mo == m && co < code)) { m = mo; mi = io; code = co; }
    }
    if ((code >> 1) == l) { if (code & 1) s1 = -3.0e38f; else s0 = -3.0e38f; }
    const float* kr = mk + (size_t)mi * EE;
    double pd = 0.0;
    #pragma unroll
    for (int i = 0; i < 8; ++i) pd += (double)q[i] * (double)kr[l + 64*i];
    #pragma unroll
    for (int o = 32; o > 0; o >>= 1) pd += __shfl_down(pd, o);
    if (l == 0) {
      double s = 2.0 * pd - sq64[mi];
      if (s > bs[4]) {
        bs[4] = s; bi[4] = mi;
        #pragma unroll
        for (int i = 4; i > 0; --i) {
          if (bs[i] > bs[i-1]) {
            double tf = bs[i]; bs[i] = bs[i-1]; bs[i-1] = tf;
            int    tx = bi[i]; bi[i] = bi[i-1]; bi[i-1] = tx;
          }
        }
      }
    }
  }
  if (l == 0) {
    #pragma unroll
    for (int i = 0; i < 5; ++i) idx5[(size_t)row*5 + i] = bi[i];
  }
}

// ---------------- unified 128x64-tile fp16 MFMA GEMM: C = A(rows) @ B^T + bias ----------------
template <int GATHER, int AF16, int OUTF32>
__global__ __launch_bounds__(256) void k_pgemm128(const int* __restrict__ gidx, const void* __restrict__ Asrc,
                                                  const f16* __restrict__ B, const float* __restrict__ bias,
                                                  void* __restrict__ outp) {
  __shared__ f16 As[128][72];
  __shared__ f16 Bs[64][72];
  const int tid = threadIdx.x;
  const int wv = tid >> 6, l = tid & 63, lc = l & 15, lp = l >> 4;
  const int m0 = blockIdx.x * 128, n0 = blockIdx.y * 64;
  const int r0 = tid >> 3;
  const int cb = (tid & 7) * 8;
  const f16*   arf[4];
  const float* ar32[4];
  #pragma unroll
  for (int v = 0; v < 4; ++v) {
    int row = m0 + r0 + v * 32;
    int gi = GATHER ? gidx[row] : row;
    if (AF16) arf[v]  = (const f16*)Asrc + (size_t)gi * EE;
    else      ar32[v] = (const float*)Asrc + (size_t)gi * EE;
  }
  const f16* br0 = B + (size_t)(n0 + r0) * EE;
  const f16* br1 = B + (size_t)(n0 + r0 + 32) * EE;
  f32x4 acc[2][4] = {{{0,0,0,0},{0,0,0,0},{0,0,0,0},{0,0,0,0}},
                     {{0,0,0,0},{0,0,0,0},{0,0,0,0},{0,0,0,0}}};
  for (int kb = 0; kb < EE; kb += 64) {
    __syncthreads();
    #pragma unroll
    for (int v = 0; v < 4; ++v) {
      if (AF16) {
        *(f16x8*)&As[r0 + v*32][cb] = *(const f16x8*)(arf[v] + kb + cb);
      } else {
        float4 x0 = *(const float4*)(ar32[v] + kb + cb);
        float4 x1 = *(const float4*)(ar32[v] + kb + cb + 4);
        f16x8 h;
        h[0]=(f16)x0.x; h[1]=(f16)x0.y; h[2]=(f16)x0.z; h[3]=(f16)x0.w;
        h[4]=(f16)x1.x; h[5]=(f16)x1.y; h[6]=(f16)x1.z; h[7]=(f16)x1.w;
        *(f16x8*)&As[r0 + v*32][cb] = h;
      }
    }
    *(f16x8*)&Bs[r0][cb]      = *(const f16x8*)(br0 + kb + cb);
    *(f16x8*)&Bs[r0 + 32][cb] = *(const f16x8*)(br1 + kb + cb);
    __syncthreads();
    #pragma unroll
    for (int ks = 0; ks < 2; ++ks) {
      f16x8 a0 = *(const f16x8*)&As[wv*32 + lc][ks*32 + lp*8];
      f16x8 a1 = *(const f16x8*)&As[wv*32 + 16 + lc][ks*32 + lp*8];
      #pragma unroll
      for (int f = 0; f < 4; ++f) {
        f16x8 b = *(const f16x8*)&Bs[f*16 + lc][ks*32 + lp*8];
        acc[0][f] = __builtin_amdgcn_mfma_f32_16x16x32_f16(a0, b, acc[0][f], 0, 0, 0);
        acc[1][f] = __builtin_amdgcn_mfma_f32_16x16x32_f16(a1, b, acc[1][f], 0, 0, 0);
      }
    }
  }
  #pragma unroll
  for (int g = 0; g < 2; ++g) {
    #pragma unroll
    for (int f = 0; f < 4; ++f) {
      int col = n0 + f*16 + lc;
      float bsv = bias[col];
      #pragma unroll
      for (int rr = 0; rr < 4; ++rr) {
        int row = m0 + wv*32 + g*16 + lp*4 + rr;
        float v = acc[g][f][rr] + bsv;
        if (OUTF32) ((float*)outp)[(size_t)row * EE + col] = v;
        else        ((f16*)outp)[(size_t)row * EE + col] = (f16)v;
      }
    }
  }
}

// ---------------- 5-key MHA (H=8, d=64), f32 compute ----------------
__global__ __launch_bounds__(256) void k_attn(const f16* __restrict__ qp, const f16* __restrict__ kp,
                                              const f16* __restrict__ vp, f16* __restrict__ ao) {
  int row = blockIdx.x * 4 + (threadIdx.x >> 6);
  int l = threadIdx.x & 63;
  int h = l >> 3, sl = l & 7;
  const f16* q = qp + (size_t)row * EE + h * 64 + sl * 8;
  float qv[8];
  #pragma unroll
  for (int i = 0; i < 8; ++i) qv[i] = (float)q[i];
  float sc[5];
  #pragma unroll
  for (int j = 0; j < 5; ++j) {
    const f16* kr = kp + ((size_t)row * 5 + j) * EE + h * 64 + sl * 8;
    float p = 0.f;
    #pragma unroll
    for (int i = 0; i < 8; ++i) p = fmaf(qv[i], (float)kr[i], p);
    p += __shfl_xor(p, 1); p += __shfl_xor(p, 2); p += __shfl_xor(p, 4);
    sc[j] = p * 0.125f;
  }
  float mx = fmaxf(fmaxf(fmaxf(sc[0], sc[1]), fmaxf(sc[2], sc[3])), sc[4]);
  float sum = 0.f;
  #pragma unroll
  for (int j = 0; j < 5; ++j) { sc[j] = __expf(sc[j] - mx); sum += sc[j]; }
  float inv = 1.0f / sum;
  float o[8] = {};
  #pragma unroll
  for (int j = 0; j < 5; ++j) {
    const f16* vr = vp + ((size_t)row * 5 + j) * EE + h * 64 + sl * 8;
    float aw = sc[j] * inv;
    #pragma unroll
    for (int i = 0; i < 8; ++i) o[i] = fmaf(aw, (float)vr[i], o[i]);
  }
  f16* dst = ao + (size_t)row * EE + h * 64 + sl * 8;
  #pragma unroll
  for (int i = 0; i < 8; ++i) dst[i] = (f16)o[i];
}

extern "C" void kernel_launch(void* const* d_in, const int* in_sizes, int n_in,
                              void* d_out, int out_size, void* d_ws, size_t ws_size,
                              hipStream_t stream) {
  const float* Q    = (const float*)d_in[0];
  const float* mk   = (const float*)d_in[1];
  const float* mv   = (const float*)d_in[2];
  const float* Wq   = (const float*)d_in[3];
  const float* bq   = (const float*)d_in[4];
  const float* Wk   = (const float*)d_in[5];
  const float* bk   = (const float*)d_in[6];
  const float* Wv   = (const float*)d_in[7];
  const float* bv   = (const float*)d_in[8];
  const float* Wiq  = (const float*)d_in[9];
  const float* Wik  = (const float*)d_in[10];
  const float* Wiv  = (const float*)d_in[11];
  const float* b_in = (const float*)d_in[12];
  const float* Wo   = (const float*)d_in[13];
  const float* bo   = (const float*)d_in[14];

  char* w = (char*)d_ws;
  size_t off = 0;
  auto alloc = [&](size_t bytes) { size_t o = off; off += (bytes + 255) & ~(size_t)255; return (void*)(w + o); };
  f16*    Kh     = (f16*)   alloc((size_t)NMEM * EE * 2);
  f16*    Qh     = (f16*)   alloc((size_t)BQ * EE * 2);   // dead after stage1 -> ao
  float*  sq32   = (float*) alloc((size_t)NMEM * 4);
  double* sq64   = (double*)alloc((size_t)NMEM * 8);
  f16*    Wc     = (f16*)   alloc((size_t)3 * EE * EE * 2);
  f16*    Wo16   = (f16*)   alloc((size_t)EE * EE * 2);
  float*  bc     = (float*) alloc((size_t)3 * EE * 4);
  int*    part_i = (int*)   alloc((size_t)BQ * NCAND * 4);
  float*  part_s = (float*) alloc((size_t)BQ * NCAND * 4);
  int*    idx5   = (int*)   alloc((size_t)BQ * 5 * 4);
  f16*    qp     = (f16*)   alloc((size_t)BQ * EE * 2);
  f16*    vp     = (f16*)   alloc((size_t)BQ * 5 * EE * 2);
  f16*    ao     = Qh;
  // big tier: separate kp + f16 value table -> gather projections read f16 (half traffic)
  size_t need_big = off + (size_t)NMEM * EE * 2 + (size_t)BQ * 5 * EE * 2 + 4096;
  bool big = (ws_size >= need_big);
  f16* Vh = nullptr;
  f16* kp;
  if (big) {
    Vh = (f16*)alloc((size_t)NMEM * EE * 2);
    kp = (f16*)alloc((size_t)BQ * 5 * EE * 2);
  } else {
    kp = Kh;   // overlay: Kh dead after stage1 in small tier
  }
  (void)in_sizes; (void)n_in; (void)out_size;

  k_prep_keys<<<NMEM / 4, 256, 0, stream>>>(mk, Kh, sq32, sq64);
  k_prep_f16<<<BQ / 4, 256, 0, stream>>>(Q, Qh);
  if (big) k_prep_f16<<<NMEM / 4, 256, 0, stream>>>(mv, Vh);
  k_compose<<<dim3(8, 8, 3), 256, 0, stream>>>(Wq, Wk, Wv, Wiq, Wik, Wiv, Wc);
  k_bias<<<3, 256, 0, stream>>>(Wiq, Wik, Wiv, bq, bk, bv, b_in, bc);
  k_cvtw<<<(EE * EE) / 256, 256, 0, stream>>>(Wo, Wo16);
  k_stage1<<<dim3(BQ / 128, NSEG), 256, 0, stream>>>(Qh, Kh, sq32, part_i, part_s);
  k_rescore<<<BQ, 64, 0, stream>>>(Q, mk, sq64, part_i, part_s, idx5);
  k_pgemm128<0,1,0><<<dim3(BQ / 128, 8), 256, 0, stream>>>(nullptr, Qh, Wc, bc, qp);
  if (big) {
    k_pgemm128<1,1,0><<<dim3(BQ * 5 / 128, 8), 256, 0, stream>>>(idx5, Kh, Wc + (size_t)EE * EE, bc + EE, kp);
    k_pgemm128<1,1,0><<<dim3(BQ * 5 / 128, 8), 256, 0, stream>>>(idx5, Vh, Wc + (size_t)2 * EE * EE, bc + 2 * EE, vp);
  } else {
    k_pgemm128<1,0,0><<<dim3(BQ * 5 / 128, 8), 256, 0, stream>>>(idx5, mk, Wc + (size_t)EE * EE, bc + EE, kp);
    k_pgemm128<1,0,0><<<dim3(BQ * 5 / 128, 8), 256, 0, stream>>>(idx5, mv, Wc + (size_t)2 * EE * EE, bc + 2 * EE, vp);
  }
  k_attn<<<BQ / 4, 256, 0, stream>>>(qp, kp, vp, ao);
  k_pgemm128<0,1,1><<<dim3(BQ / 128, 8), 256, 0, stream>>>(nullptr, ao, Wo16, bo, d_out);
}

// Round 17
// 699.860 us; speedup vs baseline: 2.1428x; 1.0388x over previous
//
#include <hip/hip_runtime.h>
#include <hip/hip_bf16.h>
#include <hip/hip_fp16.h>

typedef _Float16 f16;
typedef _Float16 f16x8 __attribute__((ext_vector_type(8)));
typedef float f32x4 __attribute__((ext_vector_type(4)));

constexpr int EE     = 512;
constexpr int NMEM   = 50000;
constexpr int BQ     = 8192;
constexpr int NSEG   = 16;
constexpr int SEGLEN = NMEM / NSEG;              // 3125 (exact)
constexpr int KVT    = 32;                       // keys per tile
constexpr int NT32   = (SEGLEN + KVT - 1) / KVT; // 98
constexpr int NC     = 5;                        // candidates kept per segment (med3 insert hard-codes 5)
constexpr int NCAND  = NSEG * NC;                // 80
constexpr int NRES   = 10;                       // exact-rescored candidates
static_assert(NC == 5, "med3 insert is specialized for NC==5");

// generic->addrspace casts for global_load_lds
typedef const __attribute__((address_space(1))) unsigned char* gas_t;
typedef __attribute__((address_space(3))) unsigned char* las_t;
__device__ static inline void g2l16(const void* g, void* l) {
  __builtin_amdgcn_global_load_lds((gas_t)g, (las_t)l, 16, 0, 0);
}

// median-of-3 (v_med3_f32); fallback composition if builtin unavailable.
// NOTE: neither path is NaN-safe -> all inserted values MUST be finite
// (round-16 bug: +inf poison -> packed NaN -> med3 corrupted the list).
#if __has_builtin(__builtin_amdgcn_fmed3f)
__device__ static inline float med3f(float a, float b, float c) {
  return __builtin_amdgcn_fmed3f(a, b, c);
}
#else
__device__ static inline float med3f(float a, float b, float c) {
  return fmaxf(fminf(a, b), fminf(fmaxf(a, b), c));
}
#endif

// pack 12-bit local index into low mantissa bits of score (compare-as-float safe:
// perturbation <= 0.125 at |score|~500, far below rank-5..10 gaps; rescore is exact)
__device__ static inline float pack_si(float s, int li) {
  return __uint_as_float((__float_as_uint(s) & 0xFFFFF000u) | (unsigned)li);
}

// ---------------- prep: f32 -> fp16 keys + f64/f32 row norms ----------------
__global__ __launch_bounds__(256) void k_prep_keys(const float* __restrict__ mk,
                                                   f16* __restrict__ kh,
                                                   float* __restrict__ sq32,
                                                   double* __restrict__ sq64) {
  int row  = blockIdx.x * 4 + (threadIdx.x >> 6);
  int lane = threadIdx.x & 63;
  const float4* src = (const float4*)(mk + (size_t)row * EE) + lane * 2;
  float4 a = src[0], b = src[1];
  double s = (double)a.x*a.x + (double)a.y*a.y + (double)a.z*a.z + (double)a.w*a.w
           + (double)b.x*b.x + (double)b.y*b.y + (double)b.z*b.z + (double)b.w*b.w;
  f16x8 h;
  h[0]=(f16)a.x; h[1]=(f16)a.y; h[2]=(f16)a.z; h[3]=(f16)a.w;
  h[4]=(f16)b.x; h[5]=(f16)b.y; h[6]=(f16)b.z; h[7]=(f16)b.w;
  *((f16x8*)(kh + (size_t)row * EE) + lane) = h;
  #pragma unroll
  for (int o = 32; o > 0; o >>= 1) s += __shfl_down(s, o);
  if (lane == 0) { sq64[row] = s; sq32[row] = (float)s; }
}

// generic f32 -> f16 row copy (rows of EE)
__global__ __launch_bounds__(256) void k_prep_f16(const float* __restrict__ src,
                                                  f16* __restrict__ dst) {
  int row  = blockIdx.x * 4 + (threadIdx.x >> 6);
  int lane = threadIdx.x & 63;
  const float4* s = (const float4*)(src + (size_t)row * EE) + lane * 2;
  float4 a = s[0], b = s[1];
  f16x8 h;
  h[0]=(f16)a.x; h[1]=(f16)a.y; h[2]=(f16)a.z; h[3]=(f16)a.w;
  h[4]=(f16)b.x; h[5]=(f16)b.y; h[6]=(f16)b.z; h[7]=(f16)b.w;
  *((f16x8*)(dst + (size_t)row * EE) + lane) = h;
}

// ---------------- compose weights: Wc_m = Win_m @ W_m (f32 acc -> fp16 out) ----------------
__global__ __launch_bounds__(256) void k_compose(const float* __restrict__ Wq, const float* __restrict__ Wk,
                                                 const float* __restrict__ Wv, const float* __restrict__ Wiq,
                                                 const float* __restrict__ Wik, const float* __restrict__ Wiv,
                                                 f16* __restrict__ Wc) {
  int m = blockIdx.z;
  const float* A = (m == 0) ? Wiq : ((m == 1) ? Wik : Wiv);
  const float* B = (m == 0) ? Wq  : ((m == 1) ? Wk  : Wv);
  f16* C = Wc + (size_t)m * EE * EE;
  __shared__ float As[64][33];
  __shared__ float Bs[32][65];
  int i0 = blockIdx.x * 64, j0 = blockIdx.y * 64;
  int tx = threadIdx.x & 15, ty = threadIdx.x >> 4;
  float acc[4][4] = {};
  for (int kb = 0; kb < EE; kb += 32) {
    __syncthreads();
    #pragma unroll
    for (int v = 0; v < 8; ++v) {
      int idx = threadIdx.x + v * 256;
      As[idx >> 5][idx & 31] = A[(size_t)(i0 + (idx >> 5)) * EE + kb + (idx & 31)];
    }
    #pragma unroll
    for (int v = 0; v < 8; ++v) {
      int idx = threadIdx.x + v * 256;
      Bs[idx >> 6][idx & 63] = B[(size_t)(kb + (idx >> 6)) * EE + j0 + (idx & 63)];
    }
    __syncthreads();
    for (int t = 0; t < 32; ++t) {
      float av[4], bv[4];
      #pragma unroll
      for (int u = 0; u < 4; ++u) av[u] = As[ty*4+u][t];
      #pragma unroll
      for (int u = 0; u < 4; ++u) bv[u] = Bs[t][tx*4+u];
      #pragma unroll
      for (int a = 0; a < 4; ++a)
        #pragma unroll
        for (int b = 0; b < 4; ++b) acc[a][b] = fmaf(av[a], bv[b], acc[a][b]);
    }
  }
  #pragma unroll
  for (int a = 0; a < 4; ++a)
    #pragma unroll
    for (int b = 0; b < 4; ++b)
      C[(size_t)(i0 + ty*4 + a) * EE + j0 + tx*4 + b] = (f16)acc[a][b];
}

__global__ void k_bias(const float* __restrict__ Wiq, const float* __restrict__ Wik,
                       const float* __restrict__ Wiv, const float* __restrict__ bqv,
                       const float* __restrict__ bkv, const float* __restrict__ bvv,
                       const float* __restrict__ b_in, float* __restrict__ bc) {
  int m = blockIdx.x;
  const float* Wi = (m == 0) ? Wiq : ((m == 1) ? Wik : Wiv);
  const float* bb = (m == 0) ? bqv : ((m == 1) ? bkv : bvv);
  for (int i = threadIdx.x; i < EE; i += blockDim.x) {
    float s = 0.f;
    for (int t = 0; t < EE; ++t) s = fmaf(Wi[(size_t)i * EE + t], bb[t], s);
    bc[m * EE + i] = s + b_in[m * EE + i];
  }
}

__global__ void k_cvtw(const float* __restrict__ W, f16* __restrict__ Wo) {
  int i = blockIdx.x * 256 + threadIdx.x;
  Wo[i] = (f16)W[i];
}

// ---------------- stage 1: swapped-operand fp16 MFMA scores, deferred med3 top-5 ----------------
__global__ __launch_bounds__(256, 2) void k_stage1(const f16* __restrict__ Qh,
                                                   const f16* __restrict__ Kh,
                                                   const float* __restrict__ sq32,
                                                   int* __restrict__ part_i,
                                                   float* __restrict__ part_s) {
  const int rb  = blockIdx.x;        // 0..63 (128 rows each)
  const int seg = blockIdx.y;        // 0..15
  const int tid = threadIdx.x;
  const int w   = tid >> 6;          // wave 0..3
  const int l   = tid & 63;
  const int lc  = l & 15, lp = l >> 4;
  const int seg_start = seg * SEGLEN;
  const int seg_end   = seg_start + SEGLEN;

  __shared__ f16   Bt[2][KVT * 520];
  __shared__ float sqs[2][KVT];

  const int rowbase = rb * 128 + w * 32;
  f16x8 a0[16], a1[16];
  {
    const f16* base0 = Qh + (size_t)(rowbase + lc) * EE + lp * 8;
    const f16* base1 = base0 + (size_t)16 * EE;
    #pragma unroll
    for (int ks = 0; ks < 16; ++ks) {
      asm volatile("global_load_dwordx4 %0, %1, off"
                   : "=v"(a0[ks]) : "v"(base0 + ks * 32) : "memory");
      asm volatile("global_load_dwordx4 %0, %1, off"
                   : "=v"(a1[ks]) : "v"(base1 + ks * 32) : "memory");
    }
    asm volatile("s_waitcnt vmcnt(0)" ::: "memory");
    __builtin_amdgcn_sched_barrier(0);
  }

  // packed lists: ts0 -> qrow rowbase+lc, ts1 -> qrow rowbase+16+lc (key-striped by lp)
  float ts0[NC], ts1[NC];
  #pragma unroll
  for (int i = 0; i < NC; ++i) { ts0[i] = -3.0e38f; ts1[i] = -3.0e38f; }
  // saved packed scores of the previous tile (selection deferred one tile)
  float sv0[8], sv1[8];
  #pragma unroll
  for (int i = 0; i < 8; ++i) { sv0[i] = -3.0e38f; sv1[i] = -3.0e38f; }

// med3 sorted insert (list descending): r0=max(t0,v), r[i]=med3(t[i-1],t[i],v).
// Each output reads only OLD values -> 5 ops, dependence depth 1 (vs 9 ops, depth 5).
// Identical result to a bubble insert FOR FINITE INPUTS (no NaN-safety!).
#define INS1(TS, PV) do { \
    float _v = (PV); \
    float _t0 = TS[0], _t1 = TS[1], _t2 = TS[2], _t3 = TS[3], _t4 = TS[4]; \
    TS[0] = fmaxf(_t0, _v); \
    TS[1] = med3f(_t0, _t1, _v); \
    TS[2] = med3f(_t1, _t2, _v); \
    TS[3] = med3f(_t2, _t3, _v); \
    TS[4] = med3f(_t3, _t4, _v); \
  } while (0)

  // stage tile tt into buffer buf: 8 rows per wave, direct global->LDS.
  // Poison is FINITE (1e38): tail scores become ~-1e38 (ordinary floats after
  // packing, never competitive with real scores O(+-2000)), keeping med3 exact.
  #define STAGE(buf, tt) do { \
      int kk = seg_start + (tt) * KVT; \
      _Pragma("unroll") \
      for (int j = 0; j < 8; ++j) { \
        int key = kk + w * 8 + j; \
        key = key < NMEM ? key : NMEM - 1; \
        g2l16(Kh + (size_t)key * EE + l * 8, &Bt[buf][(w*8 + j) * 520]); \
      } \
      if (tid < KVT) { \
        int kq = kk + tid; \
        float v = 1.0e38f; \
        if (kq < seg_end) v = sq32[kq]; \
        sqs[buf][tid] = v; \
      } \
    } while (0)

  STAGE(0, 0);
  for (int t = 0; t < NT32; ++t) {
    const int c = t & 1;
    __syncthreads();               // drains vmcnt: buf[c] staged; prior reads of buf[c^1] done
    if (t + 1 < NT32) STAGE(c ^ 1, t + 1);   // in-flight during compute; drained at next barrier

    // deferred selection of tile t-1: independent of this tile's ds_read/MFMA stream
    #pragma unroll
    for (int r = 0; r < 8; ++r) { INS1(ts0, sv0[r]); INS1(ts1, sv1[r]); }

    f32x4 A00 = {0,0,0,0}, A01 = {0,0,0,0}, A10 = {0,0,0,0}, A11 = {0,0,0,0};
    #pragma unroll
    for (int ks = 0; ks < 16; ++ks) {
      f16x8 kf0 = *(const f16x8*)&Bt[c][lc * 520 + ks * 32 + lp * 8];
      f16x8 kf1 = *(const f16x8*)&Bt[c][(16 + lc) * 520 + ks * 32 + lp * 8];
      A00 = __builtin_amdgcn_mfma_f32_16x16x32_f16(kf0, a0[ks], A00, 0, 0, 0);
      A01 = __builtin_amdgcn_mfma_f32_16x16x32_f16(kf0, a1[ks], A01, 0, 0, 0);
      A10 = __builtin_amdgcn_mfma_f32_16x16x32_f16(kf1, a0[ks], A10, 0, 0, 0);
      A11 = __builtin_amdgcn_mfma_f32_16x16x32_f16(kf1, a1[ks], A11, 0, 0, 0);
    }
    // compute + pack this tile's scores into sv (consumed at iteration t+1)
    f32x4 q0 = *(const f32x4*)&sqs[c][lp * 4];
    f32x4 q1 = *(const f32x4*)&sqs[c][16 + lp * 4];
    f32x4 s00 = 2.0f * A00 - q0;
    f32x4 s01 = 2.0f * A01 - q0;
    f32x4 s10 = 2.0f * A10 - q1;
    f32x4 s11 = 2.0f * A11 - q1;
    const int li0 = t * KVT + lp * 4;   // 12-bit local key index (<= 3135)
    const int li1 = li0 + 16;
    #pragma unroll
    for (int r = 0; r < 4; ++r) {
      sv0[r]     = pack_si(s00[r], li0 + r);
      sv0[r + 4] = pack_si(s10[r], li1 + r);
      sv1[r]     = pack_si(s01[r], li0 + r);
      sv1[r + 4] = pack_si(s11[r], li1 + r);
    }
  }
  #undef STAGE
  // epilogue: flush last tile's deferred selection
  #pragma unroll
  for (int r = 0; r < 8; ++r) { INS1(ts0, sv0[r]); INS1(ts1, sv1[r]); }

  // merge key-stripes: lanes {lc, lc+16, lc+32, lc+48} hold disjoint stripes of same q-rows
  #pragma unroll
  for (int d = 16; d <= 32; d <<= 1) {
    float os[NC];
    #pragma unroll
    for (int i = 0; i < NC; ++i) os[i] = __shfl_xor(ts0[i], d);
    #pragma unroll
    for (int j = 0; j < NC; ++j) INS1(ts0, os[j]);
    #pragma unroll
    for (int i = 0; i < NC; ++i) os[i] = __shfl_xor(ts1[i], d);
    #pragma unroll
    for (int j = 0; j < NC; ++j) INS1(ts1, os[j]);
  }
#undef INS1
  if (l < 16) {
    int row = rowbase + lc;
    #pragma unroll
    for (int i = 0; i < NC; ++i) {
      unsigned u = __float_as_uint(ts0[i]);
      part_i[(size_t)row * NCAND + seg * NC + i] = seg_start + (int)(u & 0xFFFu);
      part_s[(size_t)row * NCAND + seg * NC + i] = ts0[i];
    }
  } else if (l < 32) {
    int row = rowbase + 16 + lc;
    #pragma unroll
    for (int i = 0; i < NC; ++i) {
      unsigned u = __float_as_uint(ts1[i]);
      part_i[(size_t)row * NCAND + seg * NC + i] = seg_start + (int)(u & 0xFFFu);
      part_s[(size_t)row * NCAND + seg * NC + i] = ts1[i];
    }
  }
}

// ---------------- stage 2: noisy top-10 of 80, exact f64 rescore -> top-5 ----------------
__global__ __launch_bounds__(64) void k_rescore(const float* __restrict__ Q,
                                                const float* __restrict__ mk,
                                                const double* __restrict__ sq64,
                                                const int* __restrict__ part_i,
                                                const float* __restrict__ part_s,
                                                int* __restrict__ idx5) {
  const int row = blockIdx.x;
  const int l = threadIdx.x;
  const float* Qr = Q + (size_t)row * EE;
  float q[8];
  #pragma unroll
  for (int i = 0; i < 8; ++i) q[i] = Qr[l + 64*i];
  float s0 = part_s[(size_t)row * NCAND + l];
  int   i0 = part_i[(size_t)row * NCAND + l];
  float s1 = (l < NCAND - 64) ? part_s[(size_t)row * NCAND + 64 + l] : -3.0e38f;
  int   i1 = (l < NCAND - 64) ? part_i[(size_t)row * NCAND + 64 + l] : 0;

  double bs[5] = {-1e300, -1e300, -1e300, -1e300, -1e300};
  int    bi[5] = {0, 0, 0, 0, 0};
  #pragma unroll
  for (int p = 0; p < NRES; ++p) {
    bool pick0 = (s0 >= s1);
    float m  = pick0 ? s0 : s1;
    int   mi = pick0 ? i0 : i1;
    int   code = (l << 1) | (pick0 ? 0 : 1);
    #pragma unroll
    for (int o = 32; o > 0; o >>= 1) {
      float mo = __shfl_xor(m, o);
      int   io = __shfl_xor(mi, o);
      int   co = __shfl_xor(code, o);
      if (mo > m || (mo == m && co < code)) { m = mo; mi = io; code = co; }
    }
    if ((code >> 1) == l) { if (code & 1) s1 = -3.0e38f; else s0 = -3.0e38f; }
    const float* kr = mk + (size_t)mi * EE;
    double pd = 0.0;
    #pragma unroll
    for (int i = 0; i < 8; ++i) pd += (double)q[i] * (double)kr[l + 64*i];
    #pragma unroll
    for (int o = 32; o > 0; o >>= 1) pd += __shfl_down(pd, o);
    if (l == 0) {
      double s = 2.0 * pd - sq64[mi];
      if (s > bs[4]) {
        bs[4] = s; bi[4] = mi;
        #pragma unroll
        for (int i = 4; i > 0; --i) {
          if (bs[i] > bs[i-1]) {
            double tf = bs[i]; bs[i] = bs[i-1]; bs[i-1] = tf;
            int    tx = bi[i]; bi[i] = bi[i-1]; bi[i-1] = tx;
          }
        }
      }
    }
  }
  if (l == 0) {
    #pragma unroll
    for (int i = 0; i < 5; ++i) idx5[(size_t)row*5 + i] = bi[i];
  }
}

// ---------------- unified 128x64-tile fp16 MFMA GEMM: C = A(rows) @ B^T + bias ----------------
template <int GATHER, int AF16, int OUTF32>
__global__ __launch_bounds__(256) void k_pgemm128(const int* __restrict__ gidx, const void* __restrict__ Asrc,
                                                  const f16* __restrict__ B, const float* __restrict__ bias,
                                                  void* __restrict__ outp) {
  __shared__ f16 As[128][72];
  __shared__ f16 Bs[64][72];
  const int tid = threadIdx.x;
  const int wv = tid >> 6, l = tid & 63, lc = l & 15, lp = l >> 4;
  const int m0 = blockIdx.x * 128, n0 = blockIdx.y * 64;
  const int r0 = tid >> 3;
  const int cb = (tid & 7) * 8;
  const f16*   arf[4];
  const float* ar32[4];
  #pragma unroll
  for (int v = 0; v < 4; ++v) {
    int row = m0 + r0 + v * 32;
    int gi = GATHER ? gidx[row] : row;
    if (AF16) arf[v]  = (const f16*)Asrc + (size_t)gi * EE;
    else      ar32[v] = (const float*)Asrc + (size_t)gi * EE;
  }
  const f16* br0 = B + (size_t)(n0 + r0) * EE;
  const f16* br1 = B + (size_t)(n0 + r0 + 32) * EE;
  f32x4 acc[2][4] = {{{0,0,0,0},{0,0,0,0},{0,0,0,0},{0,0,0,0}},
                     {{0,0,0,0},{0,0,0,0},{0,0,0,0},{0,0,0,0}}};
  for (int kb = 0; kb < EE; kb += 64) {
    __syncthreads();
    #pragma unroll
    for (int v = 0; v < 4; ++v) {
      if (AF16) {
        *(f16x8*)&As[r0 + v*32][cb] = *(const f16x8*)(arf[v] + kb + cb);
      } else {
        float4 x0 = *(const float4*)(ar32[v] + kb + cb);
        float4 x1 = *(const float4*)(ar32[v] + kb + cb + 4);
        f16x8 h;
        h[0]=(f16)x0.x; h[1]=(f16)x0.y; h[2]=(f16)x0.z; h[3]=(f16)x0.w;
        h[4]=(f16)x1.x; h[5]=(f16)x1.y; h[6]=(f16)x1.z; h[7]=(f16)x1.w;
        *(f16x8*)&As[r0 + v*32][cb] = h;
      }
    }
    *(f16x8*)&Bs[r0][cb]      = *(const f16x8*)(br0 + kb + cb);
    *(f16x8*)&Bs[r0 + 32][cb] = *(const f16x8*)(br1 + kb + cb);
    __syncthreads();
    #pragma unroll
    for (int ks = 0; ks < 2; ++ks) {
      f16x8 a0 = *(const f16x8*)&As[wv*32 + lc][ks*32 + lp*8];
      f16x8 a1 = *(const f16x8*)&As[wv*32 + 16 + lc][ks*32 + lp*8];
      #pragma unroll
      for (int f = 0; f < 4; ++f) {
        f16x8 b = *(const f16x8*)&Bs[f*16 + lc][ks*32 + lp*8];
        acc[0][f] = __builtin_amdgcn_mfma_f32_16x16x32_f16(a0, b, acc[0][f], 0, 0, 0);
        acc[1][f] = __builtin_amdgcn_mfma_f32_16x16x32_f16(a1, b, acc[1][f], 0, 0, 0);
      }
    }
  }
  #pragma unroll
  for (int g = 0; g < 2; ++g) {
    #pragma unroll
    for (int f = 0; f < 4; ++f) {
      int col = n0 + f*16 + lc;
      float bsv = bias[col];
      #pragma unroll
      for (int rr = 0; rr < 4; ++rr) {
        int row = m0 + wv*32 + g*16 + lp*4 + rr;
        float v = acc[g][f][rr] + bsv;
        if (OUTF32) ((float*)outp)[(size_t)row * EE + col] = v;
        else        ((f16*)outp)[(size_t)row * EE + col] = (f16)v;
      }
    }
  }
}

// ---------------- 5-key MHA (H=8, d=64), f32 compute ----------------
__global__ __launch_bounds__(256) void k_attn(const f16* __restrict__ qp, const f16* __restrict__ kp,
                                              const f16* __restrict__ vp, f16* __restrict__ ao) {
  int row = blockIdx.x * 4 + (threadIdx.x >> 6);
  int l = threadIdx.x & 63;
  int h = l >> 3, sl = l & 7;
  const f16* q = qp + (size_t)row * EE + h * 64 + sl * 8;
  float qv[8];
  #pragma unroll
  for (int i = 0; i < 8; ++i) qv[i] = (float)q[i];
  float sc[5];
  #pragma unroll
  for (int j = 0; j < 5; ++j) {
    const f16* kr = kp + ((size_t)row * 5 + j) * EE + h * 64 + sl * 8;
    float p = 0.f;
    #pragma unroll
    for (int i = 0; i < 8; ++i) p = fmaf(qv[i], (float)kr[i], p);
    p += __shfl_xor(p, 1); p += __shfl_xor(p, 2); p += __shfl_xor(p, 4);
    sc[j] = p * 0.125f;
  }
  float mx = fmaxf(fmaxf(fmaxf(sc[0], sc[1]), fmaxf(sc[2], sc[3])), sc[4]);
  float sum = 0.f;
  #pragma unroll
  for (int j = 0; j < 5; ++j) { sc[j] = __expf(sc[j] - mx); sum += sc[j]; }
  float inv = 1.0f / sum;
  float o[8] = {};
  #pragma unroll
  for (int j = 0; j < 5; ++j) {
    const f16* vr = vp + ((size_t)row * 5 + j) * EE + h * 64 + sl * 8;
    float aw = sc[j] * inv;
    #pragma unroll
    for (int i = 0; i < 8; ++i) o[i] = fmaf(aw, (float)vr[i], o[i]);
  }
  f16* dst = ao + (size_t)row * EE + h * 64 + sl * 8;
  #pragma unroll
  for (int i = 0; i < 8; ++i) dst[i] = (f16)o[i];
}

extern "C" void kernel_launch(void* const* d_in, const int* in_sizes, int n_in,
                              void* d_out, int out_size, void* d_ws, size_t ws_size,
                              hipStream_t stream) {
  const float* Q    = (const float*)d_in[0];
  const float* mk   = (const float*)d_in[1];
  const float* mv   = (const float*)d_in[2];
  const float* Wq   = (const float*)d_in[3];
  const float* bq   = (const float*)d_in[4];
  const float* Wk   = (const float*)d_in[5];
  const float* bk   = (const float*)d_in[6];
  const float* Wv   = (const float*)d_in[7];
  const float* bv   = (const float*)d_in[8];
  const float* Wiq  = (const float*)d_in[9];
  const float* Wik  = (const float*)d_in[10];
  const float* Wiv  = (const float*)d_in[11];
  const float* b_in = (const float*)d_in[12];
  const float* Wo   = (const float*)d_in[13];
  const float* bo   = (const float*)d_in[14];

  char* w = (char*)d_ws;
  size_t off = 0;
  auto alloc = [&](size_t bytes) { size_t o = off; off += (bytes + 255) & ~(size_t)255; return (void*)(w + o); };
  f16*    Kh     = (f16*)   alloc((size_t)NMEM * EE * 2);
  f16*    Qh     = (f16*)   alloc((size_t)BQ * EE * 2);   // dead after stage1 -> ao
  float*  sq32   = (float*) alloc((size_t)NMEM * 4);
  double* sq64   = (double*)alloc((size_t)NMEM * 8);
  f16*    Wc     = (f16*)   alloc((size_t)3 * EE * EE * 2);
  f16*    Wo16   = (f16*)   alloc((size_t)EE * EE * 2);
  float*  bc     = (float*) alloc((size_t)3 * EE * 4);
  int*    part_i = (int*)   alloc((size_t)BQ * NCAND * 4);
  float*  part_s = (float*) alloc((size_t)BQ * NCAND * 4);
  int*    idx5   = (int*)   alloc((size_t)BQ * 5 * 4);
  f16*    qp     = (f16*)   alloc((size_t)BQ * EE * 2);
  f16*    vp     = (f16*)   alloc((size_t)BQ * 5 * EE * 2);
  f16*    ao     = Qh;
  // big tier: separate kp + f16 value table -> gather projections read f16 (half traffic)
  size_t need_big = off + (size_t)NMEM * EE * 2 + (size_t)BQ * 5 * EE * 2 + 4096;
  bool big = (ws_size >= need_big);
  f16* Vh = nullptr;
  f16* kp;
  if (big) {
    Vh = (f16*)alloc((size_t)NMEM * EE * 2);
    kp = (f16*)alloc((size_t)BQ * 5 * EE * 2);
  } else {
    kp = Kh;   // overlay: Kh dead after stage1 in small tier
  }
  (void)in_sizes; (void)n_in; (void)out_size;

  k_prep_keys<<<NMEM / 4, 256, 0, stream>>>(mk, Kh, sq32, sq64);
  k_prep_f16<<<BQ / 4, 256, 0, stream>>>(Q, Qh);
  if (big) k_prep_f16<<<NMEM / 4, 256, 0, stream>>>(mv, Vh);
  k_compose<<<dim3(8, 8, 3), 256, 0, stream>>>(Wq, Wk, Wv, Wiq, Wik, Wiv, Wc);
  k_bias<<<3, 256, 0, stream>>>(Wiq, Wik, Wiv, bq, bk, bv, b_in, bc);
  k_cvtw<<<(EE * EE) / 256, 256, 0, stream>>>(Wo, Wo16);
  k_stage1<<<dim3(BQ / 128, NSEG), 256, 0, stream>>>(Qh, Kh, sq32, part_i, part_s);
  k_rescore<<<BQ, 64, 0, stream>>>(Q, mk, sq64, part_i, part_s, idx5);
  k_pgemm128<0,1,0><<<dim3(BQ / 128, 8), 256, 0, stream>>>(nullptr, Qh, Wc, bc, qp);
  if (big) {
    k_pgemm128<1,1,0><<<dim3(BQ * 5 / 128, 8), 256, 0, stream>>>(idx5, Kh, Wc + (size_t)EE * EE, bc + EE, kp);
    k_pgemm128<1,1,0><<<dim3(BQ * 5 / 128, 8), 256, 0, stream>>>(idx5, Vh, Wc + (size_t)2 * EE * EE, bc + 2 * EE, vp);
  } else {
    k_pgemm128<1,0,0><<<dim3(BQ * 5 / 128, 8), 256, 0, stream>>>(idx5, mk, Wc + (size_t)EE * EE, bc + EE, kp);
    k_pgemm128<1,0,0><<<dim3(BQ * 5 / 128, 8), 256, 0, stream>>>(idx5, mv, Wc + (size_t)2 * EE * EE, bc + 2 * EE, vp);
  }
  k_attn<<<BQ / 4, 256, 0, stream>>>(qp, kp, vp, ao);
  k_pgemm128<0,1,1><<<dim3(BQ / 128, 8), 256, 0, stream>>>(nullptr, ao, Wo16, bo, d_out);
}